// Round 1
// baseline (19520.323 us; speedup 1.0000x reference)
//
#include <hip/hip_runtime.h>
#include <math.h>

#define SN 512
#define BN 128
#define HN 256
#define NSLICE 16   // slices per sample-group
#define NGRP   16   // sample groups

// ---- workspace layout (BYTE offsets) ----
#define B_EPT    ((size_t)0)          // f64 enc_proj^T [256][512]   (1,048,576 B)
#define B_XPROJ  ((size_t)1048576)    // f64 X_proj [512][1024]      (4,194,304 B)
#define B_IPROJ  ((size_t)5242880)    // f64 W_ih@init_dec [1024]    (8,192 B)
#define B_BIAS   ((size_t)5251072)    // f64 b_ih+b_hh [1024]        (8,192 B)
#define B_WIHT   ((size_t)5259264)    // f32 W_ih^T [256][1024]      (1,048,576 B)
#define B_XT     ((size_t)6307840)    // f32 x^T [256][512]          (524,288 B)
#define B_HEX    ((size_t)6832128)    // f64 h exchange [16][8*256]  (262,144 B)
#define B_WAEX   ((size_t)7094272)    // f64 hWa exchange [16][8*256](262,144 B)
#define B_LEX    ((size_t)7356416)    // f64 logits [16][8*512]      (524,288 B)
#define B_BAR    ((size_t)7880704)    // int barriers [16][512][6][16] (3,145,728 B)
#define BAR_INTS (16*512*6*16)        // 786432

// ---- dynamic LDS layout (byte offsets) ----
#define L_UNION 0        // 36864 B: pb f64[8][64][9] / pp3 f64[32][16][9] / pf f64[16][32][9]
#define L_VLD   36864    // 2048 B: v as f64 [256]
#define L_ES    38912    // 65536 B: ept slice f64 [256][32]
#define L_HF    104448   // 16640 B: h full f64 [8][260]
#define L_HWF   121088   // 16640 B: hWa full f64 [8][260]
#define L_XPRO  137728   // 4096 B: x-proj rows f64 [8][64]
#define L_MASK  141824   // 2048 B: mask chunk f64 [32][8]
#define L_CL    143872   // 1024 B: c chunk f64 [16][8]
#define L_BIAS  144896   // 512 B: bias rows f64 [64]
#define L_SEL   145408   // 64 B: selected idx [8]
#define SMEM_TOTAL 145472

// ---- f64 tanh, abs err ~1e-11, branchless (hot path: 128/thread/step) ----
// exp(-2a) = 2^t, t = -2a*log2(e); split t = n + f, exp poly on z = f*ln2.
__device__ __forceinline__ double exp2n(double t) {
    t = fmax(t, -1000.0);                       // keep exponent splice in range
    double n = __builtin_rint(t);
    double z = (t - n) * 0.69314718055994530942; // |z| <= 0.3466
    double p = 2.7557319223985890653e-6;         // 1/9!
    p = __builtin_fma(p, z, 2.4801587301587301566e-5);
    p = __builtin_fma(p, z, 1.9841269841269841253e-4);
    p = __builtin_fma(p, z, 1.3888888888888889419e-3);
    p = __builtin_fma(p, z, 8.3333333333333332177e-3);
    p = __builtin_fma(p, z, 4.1666666666666664354e-2);
    p = __builtin_fma(p, z, 1.6666666666666666574e-1);
    p = __builtin_fma(p, z, 0.5);
    p = __builtin_fma(p, z, 1.0);
    p = __builtin_fma(p, z, 1.0);
    long long ni = (long long)(int)n;            // n in [-1000, 0]
    return __longlong_as_double(__double_as_longlong(p) + (ni << 52));
}
__device__ __forceinline__ double tanh64(double x) {
    double a = fabs(x);
    double e = exp2n(a * -2.8853900817779268147);  // exp(-2a)
    double d = 1.0 + e;                             // in (1,2]
    double r = (double)__builtin_amdgcn_rcpf((float)d);
    r = r * (2.0 - d * r);
    r = r * (2.0 - d * r);                          // ~1e-16 rel
    double res = (1.0 - e) * r;
    return copysign(res, x);
}

// ---- coherent-point access helpers: bypass L1/L2 via sc0 sc1 ----
__device__ __forceinline__ void stg_sc1d(double* p, double v) {
    asm volatile("global_store_dwordx2 %0, %1, off sc0 sc1" :: "v"(p), "v"(v) : "memory");
}
__device__ __forceinline__ void waitvm() {
    asm volatile("s_waitcnt vmcnt(0)" ::: "memory");
}
__device__ __forceinline__ double2 ldg_scd2w(const double* p) {   // 16B load + wait
    double2 r;
    asm volatile("global_load_dwordx4 %0, %1, off sc0 sc1\n\ts_waitcnt vmcnt(0)"
                 : "=v"(r) : "v"(p) : "memory");
    return r;
}
__device__ __forceinline__ int ldg_sciw(const int* p) {
    int r;
    asm volatile("global_load_dword %0, %1, off sc0 sc1\n\ts_waitcnt vmcnt(0)"
                 : "=v"(r) : "v"(p) : "memory");
    return r;
}
__device__ __forceinline__ void poll_ge(int* cnt, int target) {
    while (ldg_sciw(cnt) < target) __builtin_amdgcn_s_sleep(1);
}
__device__ __forceinline__ void bar_add(int* cnt) {
    __hip_atomic_fetch_add(cnt, 1, __ATOMIC_RELAXED, __HIP_MEMORY_SCOPE_AGENT);
}

// ---------------- init kernel 1: transposes + bias + barrier zero ----------------
__global__ __launch_bounds__(256) void k_init_transpose(
    const float* __restrict__ Wih, const float* __restrict__ bih,
    const float* __restrict__ bhh, const float* __restrict__ x,
    float* __restrict__ ws)
{
    char* wsb = (char*)ws;
    float*  wiht = (float*)(wsb + B_WIHT);
    float*  xt   = (float*)(wsb + B_XT);
    double* bias = (double*)(wsb + B_BIAS);
    int*    bar  = (int*)(wsb + B_BAR);
    int i = blockIdx.x * 256 + threadIdx.x;
    if (i < 262144) {                        // W_ih^T [e][r]
        int e = i >> 10, r = i & 1023;
        wiht[i] = Wih[(size_t)r * 256 + e];
    } else if (i < 393216) {                 // x^T [e][s]
        int j = i - 262144; int e = j >> 9, s = j & 511;
        xt[j] = x[(size_t)s * 256 + e];
    } else if (i < 394240) {                 // bias (f64)
        int j = i - 393216;
        bias[j] = (double)bih[j] + (double)bhh[j];
    } else if (i < 394240 + BAR_INTS) {      // zero barriers
        bar[i - 394240] = 0;
    }
}

// ---------------- init kernel 2: projections (full f64) ----------------
__global__ __launch_bounds__(512) void k_init_proj(
    const float* __restrict__ x, const float* __restrict__ Wae,
    const float* __restrict__ ba, const float* __restrict__ idec,
    float* __restrict__ ws)
{
    char* wsb = (char*)ws;
    const float* wiht = (const float*)(wsb + B_WIHT);
    const float* xt   = (const float*)(wsb + B_XT);
    double* ept   = (double*)(wsb + B_EPT);
    double* xproj = (double*)(wsb + B_XPROJ);
    double* iproj = (double*)(wsb + B_IPROJ);
    int blk = blockIdx.x, tid = threadIdx.x;
    if (blk < 256) {
        int k = blk, s = tid;
        double a = 0.0;
        for (int e = 0; e < 256; ++e)
            a += (double)Wae[(size_t)k * 256 + e] * (double)xt[(size_t)e * 512 + s];
        ept[(size_t)k * 512 + s] = (double)ba[k] + a;
    } else if (blk < 256 + 1024) {
        int idx = blk - 256;
        int s = idx >> 1;
        int r = (idx & 1) * 512 + tid;
        double a = 0.0;
        for (int e = 0; e < 256; ++e)
            a += (double)x[(size_t)s * 256 + e] * (double)wiht[(size_t)e * 1024 + r];
        xproj[(size_t)s * 1024 + r] = a;
    } else {
        int r = (blk - 1280) * 512 + tid;
        double a = 0.0;
        for (int e = 0; e < 256; ++e)
            a += (double)idec[e] * (double)wiht[(size_t)e * 1024 + r];
        iproj[r] = a;
    }
}

// ---------------- persistent decode: 256 WGs = 16 groups x 16 slices ----------------
// Full-f64 decision path: h/c/gates, hWa, energy tanh (poly), logits, argmax of
// (logit + gumbel) in f64 -> matches the harness's float64 numpy reference to ~1e-10
// per logit, eliminating gumbel-argmax tie-flips.  Softmax normalizer for the
// reported log-prob stays f32 (threshold 38.7).
__global__ __launch_bounds__(512, 2) void k_decode(
    const float* __restrict__ gmb, const float* __restrict__ vvec,
    const float* __restrict__ Whh, const float* __restrict__ Wad,
    float* __restrict__ ws, float* __restrict__ out)
{
    extern __shared__ char smem[];
    double* pb   = (double*)(smem + L_UNION);
    double* pp3  = (double*)(smem + L_UNION);
    double* pf   = (double*)(smem + L_UNION);
    double* vLd  = (double*)(smem + L_VLD);
    double* es_l = (double*)(smem + L_ES);
    double* hf   = (double*)(smem + L_HF);
    double* hwf  = (double*)(smem + L_HWF);
    double* xpro = (double*)(smem + L_XPRO);
    double* mask = (double*)(smem + L_MASK);
    double* c_l  = (double*)(smem + L_CL);
    double* bias_l = (double*)(smem + L_BIAS);
    int*    selA = (int*)(smem + L_SEL);

    const int tid = threadIdx.x;
    const int g = blockIdx.x & 15;      // sample group (shares XCD class)
    const int q = blockIdx.x >> 4;      // slice

    char* wsb = (char*)ws;
    const double* eptG   = (const double*)(wsb + B_EPT);
    const double* xprojG = (const double*)(wsb + B_XPROJ);
    const double* biasG  = (const double*)(wsb + B_BIAS);
    const double* iprojG = (const double*)(wsb + B_IPROJ);
    double* hex  = (double*)(wsb + B_HEX)  + (size_t)g * 2048;
    double* waex = (double*)(wsb + B_WAEX) + (size_t)g * 2048;
    double* lex  = (double*)(wsb + B_LEX)  + (size_t)g * 4096;
    int*    barI = (int*)(wsb + B_BAR) + (size_t)g * 49152;

    // ---- one-time LDS fills ----
    for (int i = tid; i < 8192; i += 512) {
        int k = i >> 5, ss = i & 31;
        es_l[i] = eptG[(size_t)k * 512 + q * 32 + ss];
    }
    for (int i = tid; i < 256; i += 512) vLd[i] = (double)vvec[i];
    if (tid < 64) bias_l[tid] = biasG[((tid >> 4) << 8) + q * 16 + (tid & 15)];
    for (int i = tid; i < 256; i += 512) mask[i] = 0.0;
    for (int i = tid; i < 128; i += 512) c_l[i] = 0.0;
    for (int i = tid; i < 2080; i += 512) { hf[i] = 0.0; hwf[i] = 0.0; }
    {
        int sl = tid >> 6, rl = tid & 63;
        int rg = ((rl >> 4) << 8) + q * 16 + (rl & 15);
        xpro[sl * 64 + rl] = iprojG[rg];
    }

    // ---- W_hh slice + Wa_dec slice into registers (loop-invariant per tid) ----
    const int w = tid >> 6, lane = tid & 63;
    const int rg1 = ((lane >> 4) << 8) + q * 16 + (lane & 15);
    const int kbase = w * 32;
    float wreg[32];
    {
        const float4* wrow = (const float4*)(Whh + (size_t)rg1 * 256 + kbase);
        #pragma unroll
        for (int j = 0; j < 8; ++j) {
            float4 v4 = wrow[j];
            wreg[4 * j + 0] = v4.x; wreg[4 * j + 1] = v4.y;
            wreg[4 * j + 2] = v4.z; wreg[4 * j + 3] = v4.w;
        }
    }
    float w3[8];
    {
        const float* wr3 = Wad + (size_t)(q * 16 + (tid & 15)) * 256 + (tid >> 4) * 8;
        #pragma unroll
        for (int kk = 0; kk < 8; ++kk) w3[kk] = wr3[kk];
    }
    __syncthreads();

    double lps = 0.0;

    for (int t = 0; t < SN; ++t) {
        int* barp = barI + t * 96;   // 6 counters x 16-int stride

        // ---- gumbel prefetch (wave w <-> sample w) ----
        float gv8[8];
        {
            const float* growW = gmb + (size_t)t * (BN * SN) + (size_t)(g * 8 + w) * SN;
            #pragma unroll
            for (int j = 0; j < 8; ++j)
                gv8[j] = __builtin_nontemporal_load(growW + lane + 64 * j);
        }

        // ================= P1(A): gate partials (f64), sl 0-3 =================
        #pragma unroll
        for (int slin = 0; slin < 4; ++slin) {
            int sl = slin;
            double a0 = 0.0, a1 = 0.0, a2 = 0.0, a3 = 0.0;
            #pragma unroll
            for (int g4 = 0; g4 < 8; ++g4) {
                const double* hp = hf + sl * 260 + kbase + 4 * g4;
                double2 hA = *(const double2*)(hp);
                double2 hB = *(const double2*)(hp + 2);
                a0 += (double)wreg[4 * g4 + 0] * hA.x;
                a1 += (double)wreg[4 * g4 + 1] * hA.y;
                a2 += (double)wreg[4 * g4 + 2] * hB.x;
                a3 += (double)wreg[4 * g4 + 3] * hB.y;
            }
            pb[w * 576 + lane * 9 + sl] = ((a0 + a1) + (a2 + a3));
        }
        __syncthreads();

        // ---- P2(A): f64 LSTM cell by wave 0; publish h(A); arrive B1A ----
        if (w == 0) {
            int jl = lane & 15, slin = lane >> 4;
            int sl = slin;
            double gvv[4];
            #pragma unroll
            for (int gate = 0; gate < 4; ++gate) {
                int rl = gate * 16 + jl;
                double p0 = pb[0 * 576 + rl * 9 + sl], p1 = pb[1 * 576 + rl * 9 + sl];
                double p2 = pb[2 * 576 + rl * 9 + sl], p3 = pb[3 * 576 + rl * 9 + sl];
                double p4 = pb[4 * 576 + rl * 9 + sl], p5 = pb[5 * 576 + rl * 9 + sl];
                double p6 = pb[6 * 576 + rl * 9 + sl], p7 = pb[7 * 576 + rl * 9 + sl];
                double s8 = ((p0 + p1) + (p2 + p3)) + ((p4 + p5) + (p6 + p7));
                gvv[gate] = bias_l[rl] + xpro[sl * 64 + rl] + s8;
            }
            double si = 1.0 / (1.0 + exp(-gvv[0]));
            double sf = 1.0 / (1.0 + exp(-gvv[1]));
            double so = 1.0 / (1.0 + exp(-gvv[3]));
            double cf = sf * c_l[jl * 8 + sl] + si * tanh(gvv[2]);
            double hn = so * tanh(cf);
            c_l[jl * 8 + sl] = cf;
            stg_sc1d(&hex[sl * 256 + q * 16 + jl], hn);
            waitvm();
            if (lane == 0) bar_add(barp + 0 * 16);
        }

        // ================= P1(B): gate partials, sl 4-7 (overlaps B1A) ==
        #pragma unroll
        for (int slin = 0; slin < 4; ++slin) {
            int sl = 4 + slin;
            double a0 = 0.0, a1 = 0.0, a2 = 0.0, a3 = 0.0;
            #pragma unroll
            for (int g4 = 0; g4 < 8; ++g4) {
                const double* hp = hf + sl * 260 + kbase + 4 * g4;
                double2 hA = *(const double2*)(hp);
                double2 hB = *(const double2*)(hp + 2);
                a0 += (double)wreg[4 * g4 + 0] * hA.x;
                a1 += (double)wreg[4 * g4 + 1] * hA.y;
                a2 += (double)wreg[4 * g4 + 2] * hB.x;
                a3 += (double)wreg[4 * g4 + 3] * hB.y;
            }
            pb[w * 576 + lane * 9 + sl] = ((a0 + a1) + (a2 + a3));
        }
        __syncthreads();

        // ---- P2(B): f64 LSTM cell by wave 1; publish h(B); arrive B1B ----
        if (w == 1) {
            int jl = lane & 15, slin = lane >> 4;
            int sl = 4 + slin;
            double gvv[4];
            #pragma unroll
            for (int gate = 0; gate < 4; ++gate) {
                int rl = gate * 16 + jl;
                double p0 = pb[0 * 576 + rl * 9 + sl], p1 = pb[1 * 576 + rl * 9 + sl];
                double p2 = pb[2 * 576 + rl * 9 + sl], p3 = pb[3 * 576 + rl * 9 + sl];
                double p4 = pb[4 * 576 + rl * 9 + sl], p5 = pb[5 * 576 + rl * 9 + sl];
                double p6 = pb[6 * 576 + rl * 9 + sl], p7 = pb[7 * 576 + rl * 9 + sl];
                double s8 = ((p0 + p1) + (p2 + p3)) + ((p4 + p5) + (p6 + p7));
                gvv[gate] = bias_l[rl] + xpro[sl * 64 + rl] + s8;
            }
            double si = 1.0 / (1.0 + exp(-gvv[0]));
            double sf = 1.0 / (1.0 + exp(-gvv[1]));
            double so = 1.0 / (1.0 + exp(-gvv[3]));
            double cf = sf * c_l[jl * 8 + sl] + si * tanh(gvv[2]);
            double hn = so * tanh(cf);
            c_l[jl * 8 + sl] = cf;
            stg_sc1d(&hex[sl * 256 + q * 16 + jl], hn);
            waitvm();
            if (lane == 0) bar_add(barp + 1 * 16);
        }

        // ---- B1A poll + gather h(A) ----
        poll_ge(barp + 0 * 16, NSLICE);
        {
            int off = 2 * tid;                 // [0,1024) doubles
            int sl = off >> 8, j = off & 255;
            double2 v2 = ldg_scd2w(hex + off);
            *(double2*)(hf + sl * 260 + j) = v2;
        }
        __syncthreads();

        // ================= P3(A): hWa partials (f64), sl 0-3 =================
        {
            int kc = tid >> 4, rl = tid & 15;
            #pragma unroll
            for (int sl = 0; sl < 4; ++sl) {
                double a = 0.0;
                #pragma unroll
                for (int kk = 0; kk < 8; ++kk)
                    a += (double)w3[kk] * hf[sl * 260 + kc * 8 + kk];
                pp3[kc * 144 + rl * 9 + sl] = a;
            }
        }
        __syncthreads();
        // ---- P3(A) reduce by wave 2; publish hWa(A); arrive B2A ----
        if (w == 2) {
            int rl = lane & 15, slin = lane >> 4;
            int sl = slin;
            double s = 0.0;
            for (int kc = 0; kc < 32; ++kc) s += pp3[kc * 144 + rl * 9 + sl];
            stg_sc1d(&waex[sl * 256 + q * 16 + rl], s);
            waitvm();
            if (lane == 0) bar_add(barp + 2 * 16);
        }

        // ---- B1B poll + gather h(B) (overlaps B2A) ----
        poll_ge(barp + 1 * 16, NSLICE);
        {
            int off = 1024 + 2 * tid;
            int sl = off >> 8, j = off & 255;
            double2 v2 = ldg_scd2w(hex + off);
            *(double2*)(hf + sl * 260 + j) = v2;
        }
        __syncthreads();

        // ================= P3(B): hWa partials, sl 4-7 =================
        {
            int kc = tid >> 4, rl = tid & 15;
            #pragma unroll
            for (int slin = 0; slin < 4; ++slin) {
                int sl = 4 + slin;
                double a = 0.0;
                #pragma unroll
                for (int kk = 0; kk < 8; ++kk)
                    a += (double)w3[kk] * hf[sl * 260 + kc * 8 + kk];
                pp3[kc * 144 + rl * 9 + sl] = a;
            }
        }
        __syncthreads();
        // ---- P3(B) reduce by wave 3; publish hWa(B); arrive B2B ----
        if (w == 3) {
            int rl = lane & 15, slin = lane >> 4;
            int sl = 4 + slin;
            double s = 0.0;
            for (int kc = 0; kc < 32; ++kc) s += pp3[kc * 144 + rl * 9 + sl];
            stg_sc1d(&waex[sl * 256 + q * 16 + rl], s);
            waitvm();
            if (lane == 0) bar_add(barp + 3 * 16);
        }

        // ---- B2A poll + gather hWa(A) ----
        poll_ge(barp + 2 * 16, NSLICE);
        {
            int off = 2 * tid;
            int sl = off >> 8, j = off & 255;
            double2 v2 = ldg_scd2w(waex + off);
            *(double2*)(hwf + sl * 260 + j) = v2;
        }
        __syncthreads();

        // ================= P4(A): attention partials (f64 tanh), sl 0-3 ============
        {
            int kc4 = tid >> 5, ss = tid & 31;
            double ev[16], vd[16];
            #pragma unroll
            for (int kk = 0; kk < 16; ++kk) {
                ev[kk] = es_l[(kc4 * 16 + kk) * 32 + ss];
                vd[kk] = vLd[kc4 * 16 + kk];
            }
            #pragma unroll 1
            for (int sl = 0; sl < 4; ++sl) {
                double a = 0.0;
                #pragma unroll
                for (int j = 0; j < 8; ++j) {
                    double2 h2 = *(const double2*)(hwf + sl * 260 + kc4 * 16 + 2 * j);
                    a += vd[2 * j + 0] * tanh64(ev[2 * j + 0] + h2.x);
                    a += vd[2 * j + 1] * tanh64(ev[2 * j + 1] + h2.y);
                }
                pf[kc4 * 288 + ss * 9 + sl] = a;
            }
        }
        __syncthreads();
        // ---- P4(A) reduce by waves 0-1; publish logits(A); arrive B3A ----
        if (tid < 128) {
            int ss = tid & 31, slin = tid >> 5;
            int sl = slin;
            double u = 0.0;
            for (int kc = 0; kc < 16; ++kc) u += pf[kc * 288 + ss * 9 + sl];
            double lg = 10.0 * tanh(u);
            stg_sc1d(&lex[sl * 512 + q * 32 + ss], lg + mask[ss * 8 + sl]);
            waitvm();
            if (lane == 0) bar_add(barp + 4 * 16);
        }

        // ---- B2B poll + gather hWa(B) (overlaps B3A) ----
        poll_ge(barp + 3 * 16, NSLICE);
        {
            int off = 1024 + 2 * tid;
            int sl = off >> 8, j = off & 255;
            double2 v2 = ldg_scd2w(waex + off);
            *(double2*)(hwf + sl * 260 + j) = v2;
        }
        __syncthreads();

        // ================= P4(B): attention partials, sl 4-7 ============
        {
            int kc4 = tid >> 5, ss = tid & 31;
            double ev[16], vd[16];
            #pragma unroll
            for (int kk = 0; kk < 16; ++kk) {
                ev[kk] = es_l[(kc4 * 16 + kk) * 32 + ss];
                vd[kk] = vLd[kc4 * 16 + kk];
            }
            #pragma unroll 1
            for (int slin = 0; slin < 4; ++slin) {
                int sl = 4 + slin;
                double a = 0.0;
                #pragma unroll
                for (int j = 0; j < 8; ++j) {
                    double2 h2 = *(const double2*)(hwf + sl * 260 + kc4 * 16 + 2 * j);
                    a += vd[2 * j + 0] * tanh64(ev[2 * j + 0] + h2.x);
                    a += vd[2 * j + 1] * tanh64(ev[2 * j + 1] + h2.y);
                }
                pf[kc4 * 288 + ss * 9 + sl] = a;
            }
        }
        __syncthreads();
        // ---- P4(B) reduce by waves 0-1; publish logits(B); arrive B3B ----
        if (tid < 128) {
            int ss = tid & 31, slin = tid >> 5;
            int sl = 4 + slin;
            double u = 0.0;
            for (int kc = 0; kc < 16; ++kc) u += pf[kc * 288 + ss * 9 + sl];
            double lg = 10.0 * tanh(u);
            stg_sc1d(&lex[sl * 512 + q * 32 + ss], lg + mask[ss * 8 + sl]);
            waitvm();
            if (lane == 0) bar_add(barp + 5 * 16);
        }

        // ================= P5: f64 argmax of (logit+gumbel); wave w <-> sample w ======
        {
            poll_ge(barp + (w < 4 ? 4 : 5) * 16, 2 * NSLICE);
            const double* lrow = lex + (size_t)w * 512;
            double lv[8];
            #pragma unroll
            for (int j = 0; j < 8; ++j) {
                asm volatile("global_load_dwordx2 %0, %1, off sc0 sc1"
                             : "=v"(lv[j]) : "v"(lrow + lane + 64 * j) : "memory");
            }
            waitvm();
            __builtin_amdgcn_sched_barrier(0);   // rule-18: pin uses after vmcnt(0)
            double M = -INFINITY;
            #pragma unroll
            for (int j = 0; j < 8; ++j) M = fmax(M, lv[j]);
            #pragma unroll
            for (int off = 32; off >= 1; off >>= 1) M = fmax(M, __shfl_xor(M, off, 64));
            float se = 0.f;
            #pragma unroll
            for (int j = 0; j < 8; ++j) se += expf((float)(lv[j] - M));
            #pragma unroll
            for (int off = 32; off >= 1; off >>= 1) se += __shfl_xor(se, off, 64);
            float logS = logf(se);
            double best = -INFINITY; int bidx = 0x7fffffff; double bl = 0.0;
            #pragma unroll
            for (int j = 0; j < 8; ++j) {
                int s = lane + 64 * j;
                double cd = lv[j] + (double)gv8[j];   // softmax shift cancels in argmax
                if (cd > best || (cd == best && s < bidx)) { best = cd; bidx = s; bl = lv[j]; }
            }
            #pragma unroll
            for (int off = 32; off >= 1; off >>= 1) {
                double ob = __shfl_xor(best, off, 64);
                int    oi = __shfl_xor(bidx, off, 64);
                double ol = __shfl_xor(bl, off, 64);
                if (ob > best || (ob == best && oi < bidx)) { best = ob; bidx = oi; bl = ol; }
            }
            lps += (bl - M) - (double)logS;
            if (lane == 0) {
                selA[w] = bidx;
                if (q == 0) out[(size_t)(g * 8 + w) * SN + t] = (float)bidx;
            }
        }
        __syncthreads();
        // ---- mask update + next-step xpro gather ----
        if (tid < 256) {
            int ss = tid >> 3, sl = tid & 7;
            if (selA[sl] == q * 32 + ss) mask[ss * 8 + sl] = -INFINITY;
        }
        {
            int sl = tid >> 6, rl = tid & 63;
            int rg = ((rl >> 4) << 8) + q * 16 + (rl & 15);
            xpro[sl * 64 + rl] = xprojG[(size_t)selA[sl] * 1024 + rg];
        }
        __syncthreads();
    }
    if (q == 0 && lane == 0) out[(size_t)BN * SN + g * 8 + w] = (float)lps;
}

extern "C" void kernel_launch(void* const* d_in, const int* in_sizes, int n_in,
                              void* d_out, int out_size, void* d_ws, size_t ws_size,
                              hipStream_t stream)
{
    const float* x    = (const float*)d_in[0];
    const float* gmb  = (const float*)d_in[1];
    const float* Wih  = (const float*)d_in[2];
    const float* Whh  = (const float*)d_in[3];
    const float* bih  = (const float*)d_in[4];
    const float* bhh  = (const float*)d_in[5];
    const float* Wad  = (const float*)d_in[6];
    const float* Wae  = (const float*)d_in[7];
    const float* ba   = (const float*)d_in[8];
    const float* vvec = (const float*)d_in[9];
    const float* idec = (const float*)d_in[10];
    float* ws = (float*)d_ws;
    float* out = (float*)d_out;

    hipFuncSetAttribute(reinterpret_cast<const void*>(k_decode),
                        hipFuncAttributeMaxDynamicSharedMemorySize, SMEM_TOTAL);

    hipLaunchKernelGGL(k_init_transpose, dim3(4612), dim3(256), 0, stream,
                       Wih, bih, bhh, x, ws);
    hipLaunchKernelGGL(k_init_proj, dim3(1282), dim3(512), 0, stream,
                       x, Wae, ba, idec, ws);
    hipLaunchKernelGGL(k_decode, dim3(256), dim3(512), SMEM_TOTAL, stream,
                       gmb, vvec, Whh, Wad, ws, out);
}

// Round 2
// 13790.768 us; speedup vs baseline: 1.4155x; 1.4155x over previous
//
#include <hip/hip_runtime.h>
#include <math.h>

#define SN 512
#define BN 128
#define HN 256
#define NSLICE 16   // slices per sample-group
#define NGRP   16   // sample groups

// ---- workspace layout (BYTE offsets) ----
#define B_EPT    ((size_t)0)          // f64 Ta = tanh(enc_proj)^T [256][512]   (1,048,576 B)
#define B_XPROJ  ((size_t)1048576)    // f64 X_proj [512][1024]      (4,194,304 B)
#define B_IPROJ  ((size_t)5242880)    // f64 W_ih@init_dec [1024]    (8,192 B)
#define B_BIAS   ((size_t)5251072)    // f64 b_ih+b_hh [1024]        (8,192 B)
#define B_WIHT   ((size_t)5259264)    // f32 W_ih^T [256][1024]      (1,048,576 B)
#define B_XT     ((size_t)6307840)    // f32 x^T [256][512]          (524,288 B)
#define B_HEX    ((size_t)6832128)    // f64 h exchange [16][8*256]  (262,144 B)
#define B_WAEX   ((size_t)7094272)    // f64 Tb=tanh(hWa) exch [16][8*256] (262,144 B)
#define B_LEX    ((size_t)7356416)    // f64 logits [16][8*512]      (524,288 B)
#define B_BAR    ((size_t)7880704)    // int barriers [16][512][6][16] (3,145,728 B)
#define BAR_INTS (16*512*6*16)        // 786432

// ---- dynamic LDS layout (byte offsets) ----
#define L_UNION 0        // 36864 B: pb f64[8][64][9] / pp3 f64[32][16][9] / pf f64[16][32][9]
#define L_VLD   36864    // 2048 B: v as f64 [256]
#define L_ES    38912    // 65536 B: Ta slice f64 [256][32]
#define L_HF    104448   // 16640 B: h full f64 [8][260]
#define L_HWF   121088   // 16640 B: Tb full f64 [8][260]
#define L_XPRO  137728   // 4096 B: x-proj rows f64 [8][64]
#define L_MASK  141824   // 2048 B: mask chunk f64 [32][8]
#define L_CL    143872   // 1024 B: c chunk f64 [16][8]
#define L_BIAS  144896   // 512 B: bias rows f64 [64]
#define L_SEL   145408   // 64 B: selected idx [8]
#define SMEM_TOTAL 145472

// ---- f64 reciprocal: v_rcp_f64 seed (+ >=2^-13) + 2 Newton -> ~2^-52 ----
__device__ __forceinline__ double rcp64(double d) {
    double r;
    asm("v_rcp_f64 %0, %1" : "=v"(r) : "v"(d));
    r = __builtin_fma(__builtin_fma(-d, r, 1.0), r, r);
    r = __builtin_fma(__builtin_fma(-d, r, 1.0), r, r);
    return r;
}

// ---- exp(t*ln2-domain): 2^t for t<=0, rel err ~6e-15 (deg-11), branchless ----
__device__ __forceinline__ double exp2n(double t) {
    t = fmax(t, -1000.0);                        // keep exponent splice in range
    double n = __builtin_rint(t);
    double z = (t - n) * 0.69314718055994530942; // |z| <= 0.3466
    double p = 2.5052108385441718775e-8;         // 1/11!
    p = __builtin_fma(p, z, 2.7557319223985892511e-7);   // 1/10!
    p = __builtin_fma(p, z, 2.7557319223985890653e-6);   // 1/9!
    p = __builtin_fma(p, z, 2.4801587301587301566e-5);
    p = __builtin_fma(p, z, 1.9841269841269841253e-4);
    p = __builtin_fma(p, z, 1.3888888888888889419e-3);
    p = __builtin_fma(p, z, 8.3333333333333332177e-3);
    p = __builtin_fma(p, z, 4.1666666666666664354e-2);
    p = __builtin_fma(p, z, 1.6666666666666666574e-1);
    p = __builtin_fma(p, z, 0.5);
    p = __builtin_fma(p, z, 1.0);
    p = __builtin_fma(p, z, 1.0);
    long long ni = (long long)(int)n;            // n in [-1000, 0]
    return __longlong_as_double(__double_as_longlong(p) + (ni << 52));
}
// tanh, abs err ~3e-15, branchless
__device__ __forceinline__ double tanh64(double x) {
    double a = fabs(x);
    double e = exp2n(a * -2.8853900817779268147);  // exp(-2a)
    double r = rcp64(1.0 + e);
    return copysign((1.0 - e) * r, x);
}
// sigmoid, rel err ~1e-14, branchless
__device__ __forceinline__ double sigmoid64(double g) {
    double a = fabs(g);
    double e = exp2n(a * -1.4426950408889634074);  // exp(-a)
    double r = rcp64(1.0 + e);
    double num = (g >= 0.0) ? 1.0 : e;
    return num * r;
}

// ---- coherent-point access helpers: bypass L1/L2 via sc0 sc1 ----
__device__ __forceinline__ void stg_sc1d(double* p, double v) {
    asm volatile("global_store_dwordx2 %0, %1, off sc0 sc1" :: "v"(p), "v"(v) : "memory");
}
__device__ __forceinline__ void waitvm() {
    asm volatile("s_waitcnt vmcnt(0)" ::: "memory");
}
__device__ __forceinline__ double2 ldg_scd2w(const double* p) {   // 16B load + wait
    double2 r;
    asm volatile("global_load_dwordx4 %0, %1, off sc0 sc1\n\ts_waitcnt vmcnt(0)"
                 : "=v"(r) : "v"(p) : "memory");
    return r;
}
__device__ __forceinline__ int ldg_sciw(const int* p) {
    int r;
    asm volatile("global_load_dword %0, %1, off sc0 sc1\n\ts_waitcnt vmcnt(0)"
                 : "=v"(r) : "v"(p) : "memory");
    return r;
}
__device__ __forceinline__ void poll_ge(int* cnt, int target) {
    while (ldg_sciw(cnt) < target) __builtin_amdgcn_s_sleep(1);
}
__device__ __forceinline__ void bar_add(int* cnt) {
    __hip_atomic_fetch_add(cnt, 1, __ATOMIC_RELAXED, __HIP_MEMORY_SCOPE_AGENT);
}

// ---------------- init kernel 1: transposes + bias + barrier zero ----------------
__global__ __launch_bounds__(256) void k_init_transpose(
    const float* __restrict__ Wih, const float* __restrict__ bih,
    const float* __restrict__ bhh, const float* __restrict__ x,
    float* __restrict__ ws)
{
    char* wsb = (char*)ws;
    float*  wiht = (float*)(wsb + B_WIHT);
    float*  xt   = (float*)(wsb + B_XT);
    double* bias = (double*)(wsb + B_BIAS);
    int*    bar  = (int*)(wsb + B_BAR);
    int i = blockIdx.x * 256 + threadIdx.x;
    if (i < 262144) {                        // W_ih^T [e][r]
        int e = i >> 10, r = i & 1023;
        wiht[i] = Wih[(size_t)r * 256 + e];
    } else if (i < 393216) {                 // x^T [e][s]
        int j = i - 262144; int e = j >> 9, s = j & 511;
        xt[j] = x[(size_t)s * 256 + e];
    } else if (i < 394240) {                 // bias (f64)
        int j = i - 393216;
        bias[j] = (double)bih[j] + (double)bhh[j];
    } else if (i < 394240 + BAR_INTS) {      // zero barriers
        bar[i - 394240] = 0;
    }
}

// ---------------- init kernel 2: projections (full f64); ept stores Ta=tanh(ept) ----------------
__global__ __launch_bounds__(512) void k_init_proj(
    const float* __restrict__ x, const float* __restrict__ Wae,
    const float* __restrict__ ba, const float* __restrict__ idec,
    float* __restrict__ ws)
{
    char* wsb = (char*)ws;
    const float* wiht = (const float*)(wsb + B_WIHT);
    const float* xt   = (const float*)(wsb + B_XT);
    double* ept   = (double*)(wsb + B_EPT);
    double* xproj = (double*)(wsb + B_XPROJ);
    double* iproj = (double*)(wsb + B_IPROJ);
    int blk = blockIdx.x, tid = threadIdx.x;
    if (blk < 256) {
        int k = blk, s = tid;
        double a = 0.0;
        for (int e = 0; e < 256; ++e)
            a += (double)Wae[(size_t)k * 256 + e] * (double)xt[(size_t)e * 512 + s];
        ept[(size_t)k * 512 + s] = tanh((double)ba[k] + a);   // Ta (libm, init-time)
    } else if (blk < 256 + 1024) {
        int idx = blk - 256;
        int s = idx >> 1;
        int r = (idx & 1) * 512 + tid;
        double a = 0.0;
        for (int e = 0; e < 256; ++e)
            a += (double)x[(size_t)s * 256 + e] * (double)wiht[(size_t)e * 1024 + r];
        xproj[(size_t)s * 1024 + r] = a;
    } else {
        int r = (blk - 1280) * 512 + tid;
        double a = 0.0;
        for (int e = 0; e < 256; ++e)
            a += (double)idec[e] * (double)wiht[(size_t)e * 1024 + r];
        iproj[r] = a;
    }
}

// ---------------- persistent decode: 256 WGs = 16 groups x 16 slices ----------------
// Full-f64 decision path.  Energy tanh via the addition identity:
//   tanh(ept+hWa) = (Ta + Tb) / (1 + Ta*Tb),  Ta precomputed, Tb published by P3.
// Per-term cost: 9 f64 ops (vs ~29 for direct tanh64), error ~1e-14 per logit.
__global__ __launch_bounds__(512, 2) void k_decode(
    const float* __restrict__ gmb, const float* __restrict__ vvec,
    const float* __restrict__ Whh, const float* __restrict__ Wad,
    float* __restrict__ ws, float* __restrict__ out)
{
    extern __shared__ char smem[];
    double* pb   = (double*)(smem + L_UNION);
    double* pp3  = (double*)(smem + L_UNION);
    double* pf   = (double*)(smem + L_UNION);
    double* vLd  = (double*)(smem + L_VLD);
    double* es_l = (double*)(smem + L_ES);       // Ta slice
    double* hf   = (double*)(smem + L_HF);
    double* hwf  = (double*)(smem + L_HWF);      // Tb full
    double* xpro = (double*)(smem + L_XPRO);
    double* mask = (double*)(smem + L_MASK);
    double* c_l  = (double*)(smem + L_CL);
    double* bias_l = (double*)(smem + L_BIAS);
    int*    selA = (int*)(smem + L_SEL);

    const int tid = threadIdx.x;
    const int g = blockIdx.x & 15;      // sample group (shares XCD class)
    const int q = blockIdx.x >> 4;      // slice

    char* wsb = (char*)ws;
    const double* eptG   = (const double*)(wsb + B_EPT);
    const double* xprojG = (const double*)(wsb + B_XPROJ);
    const double* biasG  = (const double*)(wsb + B_BIAS);
    const double* iprojG = (const double*)(wsb + B_IPROJ);
    double* hex  = (double*)(wsb + B_HEX)  + (size_t)g * 2048;
    double* waex = (double*)(wsb + B_WAEX) + (size_t)g * 2048;
    double* lex  = (double*)(wsb + B_LEX)  + (size_t)g * 4096;
    int*    barI = (int*)(wsb + B_BAR) + (size_t)g * 49152;

    // ---- one-time LDS fills ----
    for (int i = tid; i < 8192; i += 512) {
        int k = i >> 5, ss = i & 31;
        es_l[i] = eptG[(size_t)k * 512 + q * 32 + ss];
    }
    for (int i = tid; i < 256; i += 512) vLd[i] = (double)vvec[i];
    if (tid < 64) bias_l[tid] = biasG[((tid >> 4) << 8) + q * 16 + (tid & 15)];
    for (int i = tid; i < 256; i += 512) mask[i] = 0.0;
    for (int i = tid; i < 128; i += 512) c_l[i] = 0.0;
    for (int i = tid; i < 2080; i += 512) { hf[i] = 0.0; hwf[i] = 0.0; }
    {
        int sl = tid >> 6, rl = tid & 63;
        int rg = ((rl >> 4) << 8) + q * 16 + (rl & 15);
        xpro[sl * 64 + rl] = iprojG[rg];
    }

    // ---- W_hh slice + Wa_dec slice into registers (loop-invariant per tid) ----
    const int w = tid >> 6, lane = tid & 63;
    const int rg1 = ((lane >> 4) << 8) + q * 16 + (lane & 15);
    const int kbase = w * 32;
    float wreg[32];
    {
        const float4* wrow = (const float4*)(Whh + (size_t)rg1 * 256 + kbase);
        #pragma unroll
        for (int j = 0; j < 8; ++j) {
            float4 v4 = wrow[j];
            wreg[4 * j + 0] = v4.x; wreg[4 * j + 1] = v4.y;
            wreg[4 * j + 2] = v4.z; wreg[4 * j + 3] = v4.w;
        }
    }
    float w3[8];
    {
        const float* wr3 = Wad + (size_t)(q * 16 + (tid & 15)) * 256 + (tid >> 4) * 8;
        #pragma unroll
        for (int kk = 0; kk < 8; ++kk) w3[kk] = wr3[kk];
    }
    __syncthreads();

    double lps = 0.0;

    for (int t = 0; t < SN; ++t) {
        int* barp = barI + t * 96;   // 6 counters x 16-int stride

        // ---- gumbel prefetch (wave w <-> sample w) ----
        float gv8[8];
        {
            const float* growW = gmb + (size_t)t * (BN * SN) + (size_t)(g * 8 + w) * SN;
            #pragma unroll
            for (int j = 0; j < 8; ++j)
                gv8[j] = __builtin_nontemporal_load(growW + lane + 64 * j);
        }

        // ================= P1(A): gate partials (f64), sl 0-3 =================
        #pragma unroll
        for (int slin = 0; slin < 4; ++slin) {
            int sl = slin;
            double a0 = 0.0, a1 = 0.0, a2 = 0.0, a3 = 0.0;
            #pragma unroll
            for (int g4 = 0; g4 < 8; ++g4) {
                const double* hp = hf + sl * 260 + kbase + 4 * g4;
                double2 hA = *(const double2*)(hp);
                double2 hB = *(const double2*)(hp + 2);
                a0 += (double)wreg[4 * g4 + 0] * hA.x;
                a1 += (double)wreg[4 * g4 + 1] * hA.y;
                a2 += (double)wreg[4 * g4 + 2] * hB.x;
                a3 += (double)wreg[4 * g4 + 3] * hB.y;
            }
            pb[w * 576 + lane * 9 + sl] = ((a0 + a1) + (a2 + a3));
        }
        __syncthreads();

        // ---- P2(A): f64 LSTM cell by wave 0; publish h(A); arrive B1A ----
        if (w == 0) {
            int jl = lane & 15, slin = lane >> 4;
            int sl = slin;
            double gvv[4];
            #pragma unroll
            for (int gate = 0; gate < 4; ++gate) {
                int rl = gate * 16 + jl;
                double p0 = pb[0 * 576 + rl * 9 + sl], p1 = pb[1 * 576 + rl * 9 + sl];
                double p2 = pb[2 * 576 + rl * 9 + sl], p3 = pb[3 * 576 + rl * 9 + sl];
                double p4 = pb[4 * 576 + rl * 9 + sl], p5 = pb[5 * 576 + rl * 9 + sl];
                double p6 = pb[6 * 576 + rl * 9 + sl], p7 = pb[7 * 576 + rl * 9 + sl];
                double s8 = ((p0 + p1) + (p2 + p3)) + ((p4 + p5) + (p6 + p7));
                gvv[gate] = bias_l[rl] + xpro[sl * 64 + rl] + s8;
            }
            double si = sigmoid64(gvv[0]);
            double sf = sigmoid64(gvv[1]);
            double so = sigmoid64(gvv[3]);
            double cf = sf * c_l[jl * 8 + sl] + si * tanh64(gvv[2]);
            double hn = so * tanh64(cf);
            c_l[jl * 8 + sl] = cf;
            stg_sc1d(&hex[sl * 256 + q * 16 + jl], hn);
            waitvm();
            if (lane == 0) bar_add(barp + 0 * 16);
        }

        // ================= P1(B): gate partials, sl 4-7 (overlaps B1A) ==
        #pragma unroll
        for (int slin = 0; slin < 4; ++slin) {
            int sl = 4 + slin;
            double a0 = 0.0, a1 = 0.0, a2 = 0.0, a3 = 0.0;
            #pragma unroll
            for (int g4 = 0; g4 < 8; ++g4) {
                const double* hp = hf + sl * 260 + kbase + 4 * g4;
                double2 hA = *(const double2*)(hp);
                double2 hB = *(const double2*)(hp + 2);
                a0 += (double)wreg[4 * g4 + 0] * hA.x;
                a1 += (double)wreg[4 * g4 + 1] * hA.y;
                a2 += (double)wreg[4 * g4 + 2] * hB.x;
                a3 += (double)wreg[4 * g4 + 3] * hB.y;
            }
            pb[w * 576 + lane * 9 + sl] = ((a0 + a1) + (a2 + a3));
        }
        __syncthreads();

        // ---- P2(B): f64 LSTM cell by wave 1; publish h(B); arrive B1B ----
        if (w == 1) {
            int jl = lane & 15, slin = lane >> 4;
            int sl = 4 + slin;
            double gvv[4];
            #pragma unroll
            for (int gate = 0; gate < 4; ++gate) {
                int rl = gate * 16 + jl;
                double p0 = pb[0 * 576 + rl * 9 + sl], p1 = pb[1 * 576 + rl * 9 + sl];
                double p2 = pb[2 * 576 + rl * 9 + sl], p3 = pb[3 * 576 + rl * 9 + sl];
                double p4 = pb[4 * 576 + rl * 9 + sl], p5 = pb[5 * 576 + rl * 9 + sl];
                double p6 = pb[6 * 576 + rl * 9 + sl], p7 = pb[7 * 576 + rl * 9 + sl];
                double s8 = ((p0 + p1) + (p2 + p3)) + ((p4 + p5) + (p6 + p7));
                gvv[gate] = bias_l[rl] + xpro[sl * 64 + rl] + s8;
            }
            double si = sigmoid64(gvv[0]);
            double sf = sigmoid64(gvv[1]);
            double so = sigmoid64(gvv[3]);
            double cf = sf * c_l[jl * 8 + sl] + si * tanh64(gvv[2]);
            double hn = so * tanh64(cf);
            c_l[jl * 8 + sl] = cf;
            stg_sc1d(&hex[sl * 256 + q * 16 + jl], hn);
            waitvm();
            if (lane == 0) bar_add(barp + 1 * 16);
        }

        // ---- B1A poll + gather h(A) ----
        poll_ge(barp + 0 * 16, NSLICE);
        {
            int off = 2 * tid;                 // [0,1024) doubles
            int sl = off >> 8, j = off & 255;
            double2 v2 = ldg_scd2w(hex + off);
            *(double2*)(hf + sl * 260 + j) = v2;
        }
        __syncthreads();

        // ================= P3(A): hWa partials (f64), sl 0-3 =================
        {
            int kc = tid >> 4, rl = tid & 15;
            #pragma unroll
            for (int sl = 0; sl < 4; ++sl) {
                double a = 0.0;
                #pragma unroll
                for (int kk = 0; kk < 8; ++kk)
                    a += (double)w3[kk] * hf[sl * 260 + kc * 8 + kk];
                pp3[kc * 144 + rl * 9 + sl] = a;
            }
        }
        __syncthreads();
        // ---- P3(A) reduce by wave 2; publish Tb(A)=tanh(hWa); arrive B2A ----
        if (w == 2) {
            int rl = lane & 15, slin = lane >> 4;
            int sl = slin;
            double s = 0.0;
            for (int kc = 0; kc < 32; ++kc) s += pp3[kc * 144 + rl * 9 + sl];
            stg_sc1d(&waex[sl * 256 + q * 16 + rl], tanh64(s));
            waitvm();
            if (lane == 0) bar_add(barp + 2 * 16);
        }

        // ---- B1B poll + gather h(B) (overlaps B2A) ----
        poll_ge(barp + 1 * 16, NSLICE);
        {
            int off = 1024 + 2 * tid;
            int sl = off >> 8, j = off & 255;
            double2 v2 = ldg_scd2w(hex + off);
            *(double2*)(hf + sl * 260 + j) = v2;
        }
        __syncthreads();

        // ================= P3(B): hWa partials, sl 4-7 =================
        {
            int kc = tid >> 4, rl = tid & 15;
            #pragma unroll
            for (int slin = 0; slin < 4; ++slin) {
                int sl = 4 + slin;
                double a = 0.0;
                #pragma unroll
                for (int kk = 0; kk < 8; ++kk)
                    a += (double)w3[kk] * hf[sl * 260 + kc * 8 + kk];
                pp3[kc * 144 + rl * 9 + sl] = a;
            }
        }
        __syncthreads();
        // ---- P3(B) reduce by wave 3; publish Tb(B); arrive B2B ----
        if (w == 3) {
            int rl = lane & 15, slin = lane >> 4;
            int sl = 4 + slin;
            double s = 0.0;
            for (int kc = 0; kc < 32; ++kc) s += pp3[kc * 144 + rl * 9 + sl];
            stg_sc1d(&waex[sl * 256 + q * 16 + rl], tanh64(s));
            waitvm();
            if (lane == 0) bar_add(barp + 3 * 16);
        }

        // ---- B2A poll + gather Tb(A) ----
        poll_ge(barp + 2 * 16, NSLICE);
        {
            int off = 2 * tid;
            int sl = off >> 8, j = off & 255;
            double2 v2 = ldg_scd2w(waex + off);
            *(double2*)(hwf + sl * 260 + j) = v2;
        }
        __syncthreads();

        // ================= P4(A): attention partials (tanh-addition), sl 0-3 ============
        {
            int kc4 = tid >> 5, ss = tid & 31;
            double ev[16], vd[16];
            #pragma unroll
            for (int kk = 0; kk < 16; ++kk) {
                ev[kk] = es_l[(kc4 * 16 + kk) * 32 + ss];   // Ta
                vd[kk] = vLd[kc4 * 16 + kk];
            }
            #pragma unroll 1
            for (int sl = 0; sl < 4; ++sl) {
                double a = 0.0;
                #pragma unroll
                for (int j = 0; j < 8; ++j) {
                    double2 h2 = *(const double2*)(hwf + sl * 260 + kc4 * 16 + 2 * j); // Tb
                    {
                        double Ta = ev[2 * j + 0], Tb = h2.x;
                        double d = __builtin_fma(Ta, Tb, 1.0);
                        double r = rcp64(d);
                        a = __builtin_fma(vd[2 * j + 0], (Ta + Tb) * r, a);
                    }
                    {
                        double Ta = ev[2 * j + 1], Tb = h2.y;
                        double d = __builtin_fma(Ta, Tb, 1.0);
                        double r = rcp64(d);
                        a = __builtin_fma(vd[2 * j + 1], (Ta + Tb) * r, a);
                    }
                }
                pf[kc4 * 288 + ss * 9 + sl] = a;
            }
        }
        __syncthreads();
        // ---- P4(A) reduce by waves 0-1; publish logits(A); arrive B3A ----
        if (tid < 128) {
            int ss = tid & 31, slin = tid >> 5;
            int sl = slin;
            double u = 0.0;
            for (int kc = 0; kc < 16; ++kc) u += pf[kc * 288 + ss * 9 + sl];
            double lg = 10.0 * tanh64(u);
            stg_sc1d(&lex[sl * 512 + q * 32 + ss], lg + mask[ss * 8 + sl]);
            waitvm();
            if (lane == 0) bar_add(barp + 4 * 16);
        }

        // ---- B2B poll + gather Tb(B) (overlaps B3A) ----
        poll_ge(barp + 3 * 16, NSLICE);
        {
            int off = 1024 + 2 * tid;
            int sl = off >> 8, j = off & 255;
            double2 v2 = ldg_scd2w(waex + off);
            *(double2*)(hwf + sl * 260 + j) = v2;
        }
        __syncthreads();

        // ================= P4(B): attention partials, sl 4-7 ============
        {
            int kc4 = tid >> 5, ss = tid & 31;
            double ev[16], vd[16];
            #pragma unroll
            for (int kk = 0; kk < 16; ++kk) {
                ev[kk] = es_l[(kc4 * 16 + kk) * 32 + ss];
                vd[kk] = vLd[kc4 * 16 + kk];
            }
            #pragma unroll 1
            for (int slin = 0; slin < 4; ++slin) {
                int sl = 4 + slin;
                double a = 0.0;
                #pragma unroll
                for (int j = 0; j < 8; ++j) {
                    double2 h2 = *(const double2*)(hwf + sl * 260 + kc4 * 16 + 2 * j);
                    {
                        double Ta = ev[2 * j + 0], Tb = h2.x;
                        double d = __builtin_fma(Ta, Tb, 1.0);
                        double r = rcp64(d);
                        a = __builtin_fma(vd[2 * j + 0], (Ta + Tb) * r, a);
                    }
                    {
                        double Ta = ev[2 * j + 1], Tb = h2.y;
                        double d = __builtin_fma(Ta, Tb, 1.0);
                        double r = rcp64(d);
                        a = __builtin_fma(vd[2 * j + 1], (Ta + Tb) * r, a);
                    }
                }
                pf[kc4 * 288 + ss * 9 + sl] = a;
            }
        }
        __syncthreads();
        // ---- P4(B) reduce by waves 0-1; publish logits(B); arrive B3B ----
        if (tid < 128) {
            int ss = tid & 31, slin = tid >> 5;
            int sl = 4 + slin;
            double u = 0.0;
            for (int kc = 0; kc < 16; ++kc) u += pf[kc * 288 + ss * 9 + sl];
            double lg = 10.0 * tanh64(u);
            stg_sc1d(&lex[sl * 512 + q * 32 + ss], lg + mask[ss * 8 + sl]);
            waitvm();
            if (lane == 0) bar_add(barp + 5 * 16);
        }

        // ================= P5: f64 argmax of (logit+gumbel); wave w <-> sample w ======
        {
            poll_ge(barp + (w < 4 ? 4 : 5) * 16, 2 * NSLICE);
            const double* lrow = lex + (size_t)w * 512;
            double lv[8];
            #pragma unroll
            for (int j = 0; j < 8; ++j) {
                asm volatile("global_load_dwordx2 %0, %1, off sc0 sc1"
                             : "=v"(lv[j]) : "v"(lrow + lane + 64 * j) : "memory");
            }
            waitvm();
            __builtin_amdgcn_sched_barrier(0);   // rule-18: pin uses after vmcnt(0)
            double M = -INFINITY;
            #pragma unroll
            for (int j = 0; j < 8; ++j) M = fmax(M, lv[j]);
            #pragma unroll
            for (int off = 32; off >= 1; off >>= 1) M = fmax(M, __shfl_xor(M, off, 64));
            float se = 0.f;
            #pragma unroll
            for (int j = 0; j < 8; ++j) se += expf((float)(lv[j] - M));
            #pragma unroll
            for (int off = 32; off >= 1; off >>= 1) se += __shfl_xor(se, off, 64);
            float logS = logf(se);
            double best = -INFINITY; int bidx = 0x7fffffff; double bl = 0.0;
            #pragma unroll
            for (int j = 0; j < 8; ++j) {
                int s = lane + 64 * j;
                double cd = lv[j] + (double)gv8[j];   // softmax shift cancels in argmax
                if (cd > best || (cd == best && s < bidx)) { best = cd; bidx = s; bl = lv[j]; }
            }
            #pragma unroll
            for (int off = 32; off >= 1; off >>= 1) {
                double ob = __shfl_xor(best, off, 64);
                int    oi = __shfl_xor(bidx, off, 64);
                double ol = __shfl_xor(bl, off, 64);
                if (ob > best || (ob == best && oi < bidx)) { best = ob; bidx = oi; bl = ol; }
            }
            lps += (bl - M) - (double)logS;
            if (lane == 0) {
                selA[w] = bidx;
                if (q == 0) out[(size_t)(g * 8 + w) * SN + t] = (float)bidx;
            }
        }
        __syncthreads();
        // ---- mask update + next-step xpro gather ----
        if (tid < 256) {
            int ss = tid >> 3, sl = tid & 7;
            if (selA[sl] == q * 32 + ss) mask[ss * 8 + sl] = -INFINITY;
        }
        {
            int sl = tid >> 6, rl = tid & 63;
            int rg = ((rl >> 4) << 8) + q * 16 + (rl & 15);
            xpro[sl * 64 + rl] = xprojG[(size_t)selA[sl] * 1024 + rg];
        }
        __syncthreads();
    }
    if (q == 0 && lane == 0) out[(size_t)BN * SN + g * 8 + w] = (float)lps;
}

extern "C" void kernel_launch(void* const* d_in, const int* in_sizes, int n_in,
                              void* d_out, int out_size, void* d_ws, size_t ws_size,
                              hipStream_t stream)
{
    const float* x    = (const float*)d_in[0];
    const float* gmb  = (const float*)d_in[1];
    const float* Wih  = (const float*)d_in[2];
    const float* Whh  = (const float*)d_in[3];
    const float* bih  = (const float*)d_in[4];
    const float* bhh  = (const float*)d_in[5];
    const float* Wad  = (const float*)d_in[6];
    const float* Wae  = (const float*)d_in[7];
    const float* ba   = (const float*)d_in[8];
    const float* vvec = (const float*)d_in[9];
    const float* idec = (const float*)d_in[10];
    float* ws = (float*)d_ws;
    float* out = (float*)d_out;

    hipFuncSetAttribute(reinterpret_cast<const void*>(k_decode),
                        hipFuncAttributeMaxDynamicSharedMemorySize, SMEM_TOTAL);

    hipLaunchKernelGGL(k_init_transpose, dim3(4612), dim3(256), 0, stream,
                       Wih, bih, bhh, x, ws);
    hipLaunchKernelGGL(k_init_proj, dim3(1282), dim3(512), 0, stream,
                       x, Wae, ba, idec, ws);
    hipLaunchKernelGGL(k_decode, dim3(256), dim3(512), SMEM_TOTAL, stream,
                       gmb, vvec, Whh, Wad, ws, out);
}

// Round 4
// 11584.672 us; speedup vs baseline: 1.6850x; 1.1904x over previous
//
#include <hip/hip_runtime.h>
#include <math.h>

#define SN 512
#define BN 128
#define HN 256
#define NSLICE 16   // slices per sample-group
#define NGRP   16   // sample groups

// ---- workspace layout (BYTE offsets) ----
#define B_EPT    ((size_t)0)          // f64 Ta = tanh(enc_proj)^T [256][512]   (1,048,576 B)
#define B_XPROJ  ((size_t)1048576)    // f64 X_proj [512][1024]      (4,194,304 B)
#define B_IPROJ  ((size_t)5242880)    // f64 W_ih@init_dec [1024]    (8,192 B)
#define B_BIAS   ((size_t)5251072)    // f64 b_ih+b_hh [1024]        (8,192 B)
#define B_WIHT   ((size_t)5259264)    // f32 W_ih^T [256][1024]      (1,048,576 B)
#define B_XT     ((size_t)6307840)    // f32 x^T [256][512]          (524,288 B)
#define B_EX     ((size_t)6832128)    // double2 tagged slots:
                                      //   hex  [16][2048]  (512 KiB)
                                      //   waex [16][2048]  (512 KiB)
                                      //   lex  [16][4096]  (1 MiB)
#define EX_SLOTS (16*(2048+2048+4096))   // 131072 slots x 16 B = 2 MiB

// ---- dynamic LDS layout (byte offsets) ----
#define L_UNION 0        // 36864 B: pb f64[8][64][9] / pp3 f64[32][16][9] / pf f64[16][32][9]
#define L_VLD   36864    // 2048 B: v as f64 [256]
#define L_ES    38912    // 65536 B: Ta slice f64 [256][32]
#define L_HF    104448   // 16640 B: h full f64 [8][260]
#define L_HWF   121088   // 16640 B: Tb full f64 [8][260]
#define L_XPRO  137728   // 4096 B: x-proj rows f64 [8][64]
#define L_MASK  141824   // 2048 B: mask chunk f64 [32][8]
#define L_CL    143872   // 1024 B: c chunk f64 [16][8]
#define L_BIAS  144896   // 512 B: bias rows f64 [64]
#define L_SEL   145408   // 64 B: selected idx [8]
#define SMEM_TOTAL 145472

// first-class LLVM vector type for asm operands (HIP double2 is a struct)
typedef double v2d __attribute__((ext_vector_type(2)));

// step tag: injective (odd multiplier), never 0 for t in [0,512)
#define TAGC 0x9E3779B97F4A7C15ULL
__device__ __forceinline__ long long d2ll(double d) { return __double_as_longlong(d); }

// ---- f64 reciprocal: v_rcp_f64 seed + 2 Newton -> ~2^-52 ----
__device__ __forceinline__ double rcp64(double d) {
    double r;
    asm("v_rcp_f64 %0, %1" : "=v"(r) : "v"(d));
    r = __builtin_fma(__builtin_fma(-d, r, 1.0), r, r);
    r = __builtin_fma(__builtin_fma(-d, r, 1.0), r, r);
    return r;
}

// ---- 2^t for t<=0, rel err ~6e-15 (deg-11), branchless ----
__device__ __forceinline__ double exp2n(double t) {
    t = fmax(t, -1000.0);                        // keep exponent splice in range
    double n = __builtin_rint(t);
    double z = (t - n) * 0.69314718055994530942; // |z| <= 0.3466
    double p = 2.5052108385441718775e-8;         // 1/11!
    p = __builtin_fma(p, z, 2.7557319223985892511e-7);
    p = __builtin_fma(p, z, 2.7557319223985890653e-6);
    p = __builtin_fma(p, z, 2.4801587301587301566e-5);
    p = __builtin_fma(p, z, 1.9841269841269841253e-4);
    p = __builtin_fma(p, z, 1.3888888888888889419e-3);
    p = __builtin_fma(p, z, 8.3333333333333332177e-3);
    p = __builtin_fma(p, z, 4.1666666666666664354e-2);
    p = __builtin_fma(p, z, 1.6666666666666666574e-1);
    p = __builtin_fma(p, z, 0.5);
    p = __builtin_fma(p, z, 1.0);
    p = __builtin_fma(p, z, 1.0);
    long long ni = (long long)(int)n;
    return __longlong_as_double(__double_as_longlong(p) + (ni << 52));
}
__device__ __forceinline__ double tanh64(double x) {
    double a = fabs(x);
    double e = exp2n(a * -2.8853900817779268147);  // exp(-2a)
    double r = rcp64(1.0 + e);
    return copysign((1.0 - e) * r, x);
}
__device__ __forceinline__ double sigmoid64(double g) {
    double a = fabs(g);
    double e = exp2n(a * -1.4426950408889634074);  // exp(-a)
    double r = rcp64(1.0 + e);
    double num = (g >= 0.0) ? 1.0 : e;
    return num * r;
}

// ---- tagged-slot publish: one 16B store {v, v^tag}; fire-and-forget ----
__device__ __forceinline__ void pub16(double2* p, double v, unsigned long long tg) {
    v2d t2;
    t2.x = v;
    t2.y = __longlong_as_double(d2ll(v) ^ (long long)tg);
    asm volatile("global_store_dwordx4 %0, %1, off sc0 sc1" :: "v"(p), "v"(t2) : "memory");
}
// ---- tagged-slot gather of 2 adjacent slots (poll until both tags match) ----
__device__ __forceinline__ void gath2(const double2* p, unsigned long long tg,
                                      double* o0, double* o1) {
    v2d a, b;
    for (;;) {
        asm volatile("global_load_dwordx4 %0, %2, off sc0 sc1\n\t"
                     "global_load_dwordx4 %1, %2, off offset:16 sc0 sc1\n\t"
                     "s_waitcnt vmcnt(0)"
                     : "=&v"(a), "=&v"(b) : "v"(p) : "memory");
        bool ok = ((d2ll(a.x) ^ d2ll(a.y)) == (long long)tg) &
                  ((d2ll(b.x) ^ d2ll(b.y)) == (long long)tg);
        if (ok) break;
        __builtin_amdgcn_s_sleep(2);
    }
    *o0 = a.x; *o1 = b.x;
}

// ---------------- init kernel 1: transposes + bias + slot-tag clear ----------------
__global__ __launch_bounds__(256) void k_init_transpose(
    const float* __restrict__ Wih, const float* __restrict__ bih,
    const float* __restrict__ bhh, const float* __restrict__ x,
    float* __restrict__ ws)
{
    char* wsb = (char*)ws;
    float*  wiht = (float*)(wsb + B_WIHT);
    float*  xt   = (float*)(wsb + B_XT);
    double* bias = (double*)(wsb + B_BIAS);
    double2* ex  = (double2*)(wsb + B_EX);
    int i = blockIdx.x * 256 + threadIdx.x;
    if (i < 262144) {                        // W_ih^T [e][r]
        int e = i >> 10, r = i & 1023;
        wiht[i] = Wih[(size_t)r * 256 + e];
    } else if (i < 393216) {                 // x^T [e][s]
        int j = i - 262144; int e = j >> 9, s = j & 511;
        xt[j] = x[(size_t)s * 256 + e];
    } else if (i < 394240) {                 // bias (f64)
        int j = i - 393216;
        bias[j] = (double)bih[j] + (double)bhh[j];
    } else if (i < 394240 + EX_SLOTS) {      // clear exchange slots: x^y=0 != TAG(t)
        double2 z; z.x = 0.0; z.y = 0.0;
        ex[i - 394240] = z;
    }
}

// ---------------- init kernel 2: projections (full f64); ept stores Ta=tanh(ept) ----------------
__global__ __launch_bounds__(512) void k_init_proj(
    const float* __restrict__ x, const float* __restrict__ Wae,
    const float* __restrict__ ba, const float* __restrict__ idec,
    float* __restrict__ ws)
{
    char* wsb = (char*)ws;
    const float* wiht = (const float*)(wsb + B_WIHT);
    const float* xt   = (const float*)(wsb + B_XT);
    double* ept   = (double*)(wsb + B_EPT);
    double* xproj = (double*)(wsb + B_XPROJ);
    double* iproj = (double*)(wsb + B_IPROJ);
    int blk = blockIdx.x, tid = threadIdx.x;
    if (blk < 256) {
        int k = blk, s = tid;
        double a = 0.0;
        for (int e = 0; e < 256; ++e)
            a += (double)Wae[(size_t)k * 256 + e] * (double)xt[(size_t)e * 512 + s];
        ept[(size_t)k * 512 + s] = tanh((double)ba[k] + a);   // Ta (libm, init-time)
    } else if (blk < 256 + 1024) {
        int idx = blk - 256;
        int s = idx >> 1;
        int r = (idx & 1) * 512 + tid;
        double a = 0.0;
        for (int e = 0; e < 256; ++e)
            a += (double)x[(size_t)s * 256 + e] * (double)wiht[(size_t)e * 1024 + r];
        xproj[(size_t)s * 1024 + r] = a;
    } else {
        int r = (blk - 1280) * 512 + tid;
        double a = 0.0;
        for (int e = 0; e < 256; ++e)
            a += (double)idec[e] * (double)wiht[(size_t)e * 1024 + r];
        iproj[r] = a;
    }
}

// ---------------- persistent decode: 256 WGs = 16 groups x 16 slices ----------------
// Tagged-slot signaling: every exchanged f64 is {v, v^TAG(t)}; consumers poll the
// data slot directly.  No counters, no producer drain, no separate poll leg.
__global__ __launch_bounds__(512, 2) void k_decode(
    const float* __restrict__ gmb, const float* __restrict__ vvec,
    const float* __restrict__ Whh, const float* __restrict__ Wad,
    float* __restrict__ ws, float* __restrict__ out)
{
    extern __shared__ char smem[];
    double* pb   = (double*)(smem + L_UNION);
    double* pp3  = (double*)(smem + L_UNION);
    double* pf   = (double*)(smem + L_UNION);
    double* vLd  = (double*)(smem + L_VLD);
    double* es_l = (double*)(smem + L_ES);       // Ta slice
    double* hf   = (double*)(smem + L_HF);
    double* hwf  = (double*)(smem + L_HWF);      // Tb full
    double* xpro = (double*)(smem + L_XPRO);
    double* mask = (double*)(smem + L_MASK);
    double* c_l  = (double*)(smem + L_CL);
    double* bias_l = (double*)(smem + L_BIAS);
    int*    selA = (int*)(smem + L_SEL);

    const int tid = threadIdx.x;
    const int g = blockIdx.x & 15;      // sample group
    const int q = blockIdx.x >> 4;      // slice

    char* wsb = (char*)ws;
    const double* eptG   = (const double*)(wsb + B_EPT);
    const double* xprojG = (const double*)(wsb + B_XPROJ);
    const double* biasG  = (const double*)(wsb + B_BIAS);
    const double* iprojG = (const double*)(wsb + B_IPROJ);
    double2* exB    = (double2*)(wsb + B_EX);
    double2* hexD2  = exB + (size_t)g * 2048;
    double2* waexD2 = exB + 32768 + (size_t)g * 2048;
    double2* lexD2  = exB + 65536 + (size_t)g * 4096;

    // ---- one-time LDS fills ----
    for (int i = tid; i < 8192; i += 512) {
        int k = i >> 5, ss = i & 31;
        es_l[i] = eptG[(size_t)k * 512 + q * 32 + ss];
    }
    for (int i = tid; i < 256; i += 512) vLd[i] = (double)vvec[i];
    if (tid < 64) bias_l[tid] = biasG[((tid >> 4) << 8) + q * 16 + (tid & 15)];
    for (int i = tid; i < 256; i += 512) mask[i] = 0.0;
    for (int i = tid; i < 128; i += 512) c_l[i] = 0.0;
    for (int i = tid; i < 2080; i += 512) { hf[i] = 0.0; hwf[i] = 0.0; }
    {
        int sl = tid >> 6, rl = tid & 63;
        int rg = ((rl >> 4) << 8) + q * 16 + (rl & 15);
        xpro[sl * 64 + rl] = iprojG[rg];
    }

    // ---- W_hh slice + Wa_dec slice into registers (loop-invariant per tid) ----
    const int w = tid >> 6, lane = tid & 63;
    const int rg1 = ((lane >> 4) << 8) + q * 16 + (lane & 15);
    const int kbase = w * 32;
    float wreg[32];
    {
        const float4* wrow = (const float4*)(Whh + (size_t)rg1 * 256 + kbase);
        #pragma unroll
        for (int j = 0; j < 8; ++j) {
            float4 v4 = wrow[j];
            wreg[4 * j + 0] = v4.x; wreg[4 * j + 1] = v4.y;
            wreg[4 * j + 2] = v4.z; wreg[4 * j + 3] = v4.w;
        }
    }
    float w3[8];
    {
        const float* wr3 = Wad + (size_t)(q * 16 + (tid & 15)) * 256 + (tid >> 4) * 8;
        #pragma unroll
        for (int kk = 0; kk < 8; ++kk) w3[kk] = wr3[kk];
    }
    __syncthreads();

    double lps = 0.0;

    for (int t = 0; t < SN; ++t) {
        const unsigned long long tg = (unsigned long long)(t + 2) * TAGC;

        // ---- gumbel prefetch (wave w <-> sample w) ----
        float gv8[8];
        {
            const float* growW = gmb + (size_t)t * (BN * SN) + (size_t)(g * 8 + w) * SN;
            #pragma unroll
            for (int j = 0; j < 8; ++j)
                gv8[j] = __builtin_nontemporal_load(growW + lane + 64 * j);
        }

        // ================= P1(A): gate partials (f64), sl 0-3 =================
        #pragma unroll
        for (int slin = 0; slin < 4; ++slin) {
            int sl = slin;
            double a0 = 0.0, a1 = 0.0, a2 = 0.0, a3 = 0.0;
            #pragma unroll
            for (int g4 = 0; g4 < 8; ++g4) {
                const double* hp = hf + sl * 260 + kbase + 4 * g4;
                double2 hA = *(const double2*)(hp);
                double2 hB = *(const double2*)(hp + 2);
                a0 += (double)wreg[4 * g4 + 0] * hA.x;
                a1 += (double)wreg[4 * g4 + 1] * hA.y;
                a2 += (double)wreg[4 * g4 + 2] * hB.x;
                a3 += (double)wreg[4 * g4 + 3] * hB.y;
            }
            pb[w * 576 + lane * 9 + sl] = ((a0 + a1) + (a2 + a3));
        }
        __syncthreads();

        // ---- P2(A): f64 LSTM cell by wave 0; publish h(A) tagged ----
        if (w == 0) {
            int jl = lane & 15, slin = lane >> 4;
            int sl = slin;
            double gvv[4];
            #pragma unroll
            for (int gate = 0; gate < 4; ++gate) {
                int rl = gate * 16 + jl;
                double p0 = pb[0 * 576 + rl * 9 + sl], p1 = pb[1 * 576 + rl * 9 + sl];
                double p2 = pb[2 * 576 + rl * 9 + sl], p3 = pb[3 * 576 + rl * 9 + sl];
                double p4 = pb[4 * 576 + rl * 9 + sl], p5 = pb[5 * 576 + rl * 9 + sl];
                double p6 = pb[6 * 576 + rl * 9 + sl], p7 = pb[7 * 576 + rl * 9 + sl];
                double s8 = ((p0 + p1) + (p2 + p3)) + ((p4 + p5) + (p6 + p7));
                gvv[gate] = bias_l[rl] + xpro[sl * 64 + rl] + s8;
            }
            double si = sigmoid64(gvv[0]);
            double sf = sigmoid64(gvv[1]);
            double so = sigmoid64(gvv[3]);
            double cf = sf * c_l[jl * 8 + sl] + si * tanh64(gvv[2]);
            double hn = so * tanh64(cf);
            c_l[jl * 8 + sl] = cf;
            pub16(&hexD2[sl * 256 + q * 16 + jl], hn, tg);
        }

        // ================= P1(B): gate partials, sl 4-7 =================
        #pragma unroll
        for (int slin = 0; slin < 4; ++slin) {
            int sl = 4 + slin;
            double a0 = 0.0, a1 = 0.0, a2 = 0.0, a3 = 0.0;
            #pragma unroll
            for (int g4 = 0; g4 < 8; ++g4) {
                const double* hp = hf + sl * 260 + kbase + 4 * g4;
                double2 hA = *(const double2*)(hp);
                double2 hB = *(const double2*)(hp + 2);
                a0 += (double)wreg[4 * g4 + 0] * hA.x;
                a1 += (double)wreg[4 * g4 + 1] * hA.y;
                a2 += (double)wreg[4 * g4 + 2] * hB.x;
                a3 += (double)wreg[4 * g4 + 3] * hB.y;
            }
            pb[w * 576 + lane * 9 + sl] = ((a0 + a1) + (a2 + a3));
        }
        __syncthreads();

        // ---- P2(B): f64 LSTM cell by wave 1; publish h(B) tagged ----
        if (w == 1) {
            int jl = lane & 15, slin = lane >> 4;
            int sl = 4 + slin;
            double gvv[4];
            #pragma unroll
            for (int gate = 0; gate < 4; ++gate) {
                int rl = gate * 16 + jl;
                double p0 = pb[0 * 576 + rl * 9 + sl], p1 = pb[1 * 576 + rl * 9 + sl];
                double p2 = pb[2 * 576 + rl * 9 + sl], p3 = pb[3 * 576 + rl * 9 + sl];
                double p4 = pb[4 * 576 + rl * 9 + sl], p5 = pb[5 * 576 + rl * 9 + sl];
                double p6 = pb[6 * 576 + rl * 9 + sl], p7 = pb[7 * 576 + rl * 9 + sl];
                double s8 = ((p0 + p1) + (p2 + p3)) + ((p4 + p5) + (p6 + p7));
                gvv[gate] = bias_l[rl] + xpro[sl * 64 + rl] + s8;
            }
            double si = sigmoid64(gvv[0]);
            double sf = sigmoid64(gvv[1]);
            double so = sigmoid64(gvv[3]);
            double cf = sf * c_l[jl * 8 + sl] + si * tanh64(gvv[2]);
            double hn = so * tanh64(cf);
            c_l[jl * 8 + sl] = cf;
            pub16(&hexD2[sl * 256 + q * 16 + jl], hn, tg);
        }

        // ---- gather h(A): poll tagged slots ----
        {
            int off = 2 * tid;                 // [0,1024)
            int sl = off >> 8, j = off & 255;
            gath2(hexD2 + off, tg, &hf[sl * 260 + j], &hf[sl * 260 + j + 1]);
        }
        __syncthreads();

        // ================= P3(A): hWa partials (f64), sl 0-3 =================
        {
            int kc = tid >> 4, rl = tid & 15;
            #pragma unroll
            for (int sl = 0; sl < 4; ++sl) {
                double a = 0.0;
                #pragma unroll
                for (int kk = 0; kk < 8; ++kk)
                    a += (double)w3[kk] * hf[sl * 260 + kc * 8 + kk];
                pp3[kc * 144 + rl * 9 + sl] = a;
            }
        }
        __syncthreads();
        // ---- P3(A) reduce by wave 2; publish Tb(A)=tanh(hWa) tagged ----
        if (w == 2) {
            int rl = lane & 15, slin = lane >> 4;
            int sl = slin;
            double s = 0.0;
            for (int kc = 0; kc < 32; ++kc) s += pp3[kc * 144 + rl * 9 + sl];
            pub16(&waexD2[sl * 256 + q * 16 + rl], tanh64(s), tg);
        }

        // ---- gather h(B) ----
        {
            int off = 1024 + 2 * tid;
            int sl = off >> 8, j = off & 255;
            gath2(hexD2 + off, tg, &hf[sl * 260 + j], &hf[sl * 260 + j + 1]);
        }
        __syncthreads();

        // ================= P3(B): hWa partials, sl 4-7 =================
        {
            int kc = tid >> 4, rl = tid & 15;
            #pragma unroll
            for (int slin = 0; slin < 4; ++slin) {
                int sl = 4 + slin;
                double a = 0.0;
                #pragma unroll
                for (int kk = 0; kk < 8; ++kk)
                    a += (double)w3[kk] * hf[sl * 260 + kc * 8 + kk];
                pp3[kc * 144 + rl * 9 + sl] = a;
            }
        }
        __syncthreads();
        // ---- P3(B) reduce by wave 3; publish Tb(B) tagged ----
        if (w == 3) {
            int rl = lane & 15, slin = lane >> 4;
            int sl = 4 + slin;
            double s = 0.0;
            for (int kc = 0; kc < 32; ++kc) s += pp3[kc * 144 + rl * 9 + sl];
            pub16(&waexD2[sl * 256 + q * 16 + rl], tanh64(s), tg);
        }

        // ---- gather Tb(A) ----
        {
            int off = 2 * tid;
            int sl = off >> 8, j = off & 255;
            gath2(waexD2 + off, tg, &hwf[sl * 260 + j], &hwf[sl * 260 + j + 1]);
        }
        __syncthreads();

        // ================= P4(A): attention partials (tanh-addition), sl 0-3 ============
        {
            int kc4 = tid >> 5, ss = tid & 31;
            double ev[16], vd[16];
            #pragma unroll
            for (int kk = 0; kk < 16; ++kk) {
                ev[kk] = es_l[(kc4 * 16 + kk) * 32 + ss];   // Ta
                vd[kk] = vLd[kc4 * 16 + kk];
            }
            #pragma unroll 1
            for (int sl = 0; sl < 4; ++sl) {
                double a = 0.0;
                #pragma unroll
                for (int j = 0; j < 8; ++j) {
                    double2 h2 = *(const double2*)(hwf + sl * 260 + kc4 * 16 + 2 * j); // Tb
                    {
                        double Ta = ev[2 * j + 0], Tb = h2.x;
                        double d = __builtin_fma(Ta, Tb, 1.0);
                        double r = rcp64(d);
                        a = __builtin_fma(vd[2 * j + 0], (Ta + Tb) * r, a);
                    }
                    {
                        double Ta = ev[2 * j + 1], Tb = h2.y;
                        double d = __builtin_fma(Ta, Tb, 1.0);
                        double r = rcp64(d);
                        a = __builtin_fma(vd[2 * j + 1], (Ta + Tb) * r, a);
                    }
                }
                pf[kc4 * 288 + ss * 9 + sl] = a;
            }
        }
        __syncthreads();
        // ---- P4(A) reduce by waves 0-1; publish logits(A) tagged ----
        if (tid < 128) {
            int ss = tid & 31, slin = tid >> 5;
            int sl = slin;
            double u = 0.0;
            for (int kc = 0; kc < 16; ++kc) u += pf[kc * 288 + ss * 9 + sl];
            double lg = 10.0 * tanh64(u);
            pub16(&lexD2[sl * 512 + q * 32 + ss], lg + mask[ss * 8 + sl], tg);
        }

        // ---- gather Tb(B) ----
        {
            int off = 1024 + 2 * tid;
            int sl = off >> 8, j = off & 255;
            gath2(waexD2 + off, tg, &hwf[sl * 260 + j], &hwf[sl * 260 + j + 1]);
        }
        __syncthreads();

        // ================= P4(B): attention partials, sl 4-7 ============
        {
            int kc4 = tid >> 5, ss = tid & 31;
            double ev[16], vd[16];
            #pragma unroll
            for (int kk = 0; kk < 16; ++kk) {
                ev[kk] = es_l[(kc4 * 16 + kk) * 32 + ss];
                vd[kk] = vLd[kc4 * 16 + kk];
            }
            #pragma unroll 1
            for (int slin = 0; slin < 4; ++slin) {
                int sl = 4 + slin;
                double a = 0.0;
                #pragma unroll
                for (int j = 0; j < 8; ++j) {
                    double2 h2 = *(const double2*)(hwf + sl * 260 + kc4 * 16 + 2 * j);
                    {
                        double Ta = ev[2 * j + 0], Tb = h2.x;
                        double d = __builtin_fma(Ta, Tb, 1.0);
                        double r = rcp64(d);
                        a = __builtin_fma(vd[2 * j + 0], (Ta + Tb) * r, a);
                    }
                    {
                        double Ta = ev[2 * j + 1], Tb = h2.y;
                        double d = __builtin_fma(Ta, Tb, 1.0);
                        double r = rcp64(d);
                        a = __builtin_fma(vd[2 * j + 1], (Ta + Tb) * r, a);
                    }
                }
                pf[kc4 * 288 + ss * 9 + sl] = a;
            }
        }
        __syncthreads();
        // ---- P4(B) reduce by waves 0-1; publish logits(B) tagged ----
        if (tid < 128) {
            int ss = tid & 31, slin = tid >> 5;
            int sl = 4 + slin;
            double u = 0.0;
            for (int kc = 0; kc < 16; ++kc) u += pf[kc * 288 + ss * 9 + sl];
            double lg = 10.0 * tanh64(u);
            pub16(&lexD2[sl * 512 + q * 32 + ss], lg + mask[ss * 8 + sl], tg);
        }

        // ================= P5: poll 8 tagged logit slots; f64 argmax ======
        {
            const double2* b0 = lexD2 + (size_t)w * 512 + lane;
            const double2* b1 = b0 + 256;
            double lv[8];
            for (;;) {
                v2d q0, q1, q2, q3, q4, q5, q6, q7;
                asm volatile(
                    "global_load_dwordx4 %0, %8, off sc0 sc1\n\t"
                    "global_load_dwordx4 %1, %8, off offset:1024 sc0 sc1\n\t"
                    "global_load_dwordx4 %2, %8, off offset:2048 sc0 sc1\n\t"
                    "global_load_dwordx4 %3, %8, off offset:3072 sc0 sc1\n\t"
                    "global_load_dwordx4 %4, %9, off sc0 sc1\n\t"
                    "global_load_dwordx4 %5, %9, off offset:1024 sc0 sc1\n\t"
                    "global_load_dwordx4 %6, %9, off offset:2048 sc0 sc1\n\t"
                    "global_load_dwordx4 %7, %9, off offset:3072 sc0 sc1\n\t"
                    "s_waitcnt vmcnt(0)"
                    : "=&v"(q0), "=&v"(q1), "=&v"(q2), "=&v"(q3),
                      "=&v"(q4), "=&v"(q5), "=&v"(q6), "=&v"(q7)
                    : "v"(b0), "v"(b1) : "memory");
                bool ok = ((d2ll(q0.x) ^ d2ll(q0.y)) == (long long)tg) &
                          ((d2ll(q1.x) ^ d2ll(q1.y)) == (long long)tg) &
                          ((d2ll(q2.x) ^ d2ll(q2.y)) == (long long)tg) &
                          ((d2ll(q3.x) ^ d2ll(q3.y)) == (long long)tg) &
                          ((d2ll(q4.x) ^ d2ll(q4.y)) == (long long)tg) &
                          ((d2ll(q5.x) ^ d2ll(q5.y)) == (long long)tg) &
                          ((d2ll(q6.x) ^ d2ll(q6.y)) == (long long)tg) &
                          ((d2ll(q7.x) ^ d2ll(q7.y)) == (long long)tg);
                if (ok) {
                    lv[0] = q0.x; lv[1] = q1.x; lv[2] = q2.x; lv[3] = q3.x;
                    lv[4] = q4.x; lv[5] = q5.x; lv[6] = q6.x; lv[7] = q7.x;
                    break;
                }
                __builtin_amdgcn_s_sleep(2);
            }
            double M = -INFINITY;
            #pragma unroll
            for (int j = 0; j < 8; ++j) M = fmax(M, lv[j]);
            #pragma unroll
            for (int off = 32; off >= 1; off >>= 1) M = fmax(M, __shfl_xor(M, off, 64));
            float se = 0.f;
            #pragma unroll
            for (int j = 0; j < 8; ++j) se += expf((float)(lv[j] - M));
            #pragma unroll
            for (int off = 32; off >= 1; off >>= 1) se += __shfl_xor(se, off, 64);
            float logS = logf(se);
            double best = -INFINITY; int bidx = 0x7fffffff; double bl = 0.0;
            #pragma unroll
            for (int j = 0; j < 8; ++j) {
                int s = lane + 64 * j;
                double cd = lv[j] + (double)gv8[j];   // softmax shift cancels in argmax
                if (cd > best || (cd == best && s < bidx)) { best = cd; bidx = s; bl = lv[j]; }
            }
            #pragma unroll
            for (int off = 32; off >= 1; off >>= 1) {
                double ob = __shfl_xor(best, off, 64);
                int    oi = __shfl_xor(bidx, off, 64);
                double ol = __shfl_xor(bl, off, 64);
                if (ob > best || (ob == best && oi < bidx)) { best = ob; bidx = oi; bl = ol; }
            }
            lps += (bl - M) - (double)logS;
            if (lane == 0) {
                selA[w] = bidx;
                if (q == 0) out[(size_t)(g * 8 + w) * SN + t] = (float)bidx;
            }
        }
        __syncthreads();
        // ---- mask update + next-step xpro gather ----
        if (tid < 256) {
            int ss = tid >> 3, sl = tid & 7;
            if (selA[sl] == q * 32 + ss) mask[ss * 8 + sl] = -INFINITY;
        }
        {
            int sl = tid >> 6, rl = tid & 63;
            int rg = ((rl >> 4) << 8) + q * 16 + (rl & 15);
            xpro[sl * 64 + rl] = xprojG[(size_t)selA[sl] * 1024 + rg];
        }
        __syncthreads();
    }
    if (q == 0 && lane == 0) out[(size_t)BN * SN + g * 8 + w] = (float)lps;
}

extern "C" void kernel_launch(void* const* d_in, const int* in_sizes, int n_in,
                              void* d_out, int out_size, void* d_ws, size_t ws_size,
                              hipStream_t stream)
{
    const float* x    = (const float*)d_in[0];
    const float* gmb  = (const float*)d_in[1];
    const float* Wih  = (const float*)d_in[2];
    const float* Whh  = (const float*)d_in[3];
    const float* bih  = (const float*)d_in[4];
    const float* bhh  = (const float*)d_in[5];
    const float* Wad  = (const float*)d_in[6];
    const float* Wae  = (const float*)d_in[7];
    const float* ba   = (const float*)d_in[8];
    const float* vvec = (const float*)d_in[9];
    const float* idec = (const float*)d_in[10];
    float* ws = (float*)d_ws;
    float* out = (float*)d_out;

    hipFuncSetAttribute(reinterpret_cast<const void*>(k_decode),
                        hipFuncAttributeMaxDynamicSharedMemorySize, SMEM_TOTAL);

    hipLaunchKernelGGL(k_init_transpose, dim3(2052), dim3(256), 0, stream,
                       Wih, bih, bhh, x, ws);
    hipLaunchKernelGGL(k_init_proj, dim3(1282), dim3(512), 0, stream,
                       x, Wae, ba, idec, ws);
    hipLaunchKernelGGL(k_decode, dim3(256), dim3(512), SMEM_TOTAL, stream,
                       gmb, vvec, Whh, Wad, ws, out);
}

// Round 5
// 8884.547 us; speedup vs baseline: 2.1971x; 1.3039x over previous
//
#include <hip/hip_runtime.h>
#include <math.h>

#define SN 512
#define BN 128
#define HN 256
#define NSLICE 16   // slices per sample-group
#define NGRP   16   // sample groups

// ---- workspace layout (BYTE offsets) ----
#define B_EPT    ((size_t)0)          // f64 Ta = tanh(enc_proj)^T [256][512]   (1,048,576 B)
#define B_XPROJ  ((size_t)1048576)    // f64 X_proj [512][1024]      (4,194,304 B)
#define B_IPROJ  ((size_t)5242880)    // f64 W_ih@init_dec [1024]    (8,192 B)
#define B_BIAS   ((size_t)5251072)    // f64 b_ih+b_hh [1024]        (8,192 B)
#define B_WIHT   ((size_t)5259264)    // f32 W_ih^T [256][1024]      (1,048,576 B)
#define B_XT     ((size_t)6307840)    // f32 x^T [256][512]          (524,288 B)
#define B_EX     ((size_t)6832128)    // double2 tagged slots x2 parities:
                                      //   per parity: hex[16][2048] waex[16][2048] lex[16][4096]
#define PAR_STRIDE 131072             // slots per parity
#define EX_SLOTS  (2*PAR_STRIDE)      // 262144 slots x 16 B = 4 MiB

// ---- dynamic LDS layout (byte offsets) — fully de-aliased ----
#define L_PB    0        // 36864 B: pb  f64[8][64][9]
#define L_PP3   36864    // 36864 B: pp3 f64[32][16][9]
#define L_PF    73728    // 36864 B: pf  f64[16][32][9]
#define L_VLD   110592   // 2048 B: v as f64 [256]
#define L_HF    112640   // 16640 B: h full f64 [8][260]
#define L_HWF   129280   // 16640 B: Tb full f64 [8][260]
#define L_XPRO  145920   // 4096 B: x-proj rows f64 [8][64]
#define L_MASK  150016   // 2048 B: mask chunk f64 [32][8]
#define L_CL    152064   // 1024 B: c chunk f64 [16][8]
#define L_BIAS  153088   // 512 B: bias rows f64 [64]
#define L_SEL   153600   // 64 B: selected idx [8]
#define SMEM_TOTAL 153664

// first-class LLVM vector type for asm operands (HIP double2 is a struct)
typedef double v2d __attribute__((ext_vector_type(2)));

// step tag: injective (odd multiplier), never 0 for t in [0,512)
#define TAGC 0x9E3779B97F4A7C15ULL
__device__ __forceinline__ long long d2ll(double d) { return __double_as_longlong(d); }

// ---- f64 reciprocal: v_rcp_f64 seed + 2 Newton -> ~2^-52 (state path) ----
__device__ __forceinline__ double rcp64(double d) {
    double r;
    asm("v_rcp_f64 %0, %1" : "=v"(r) : "v"(d));
    r = __builtin_fma(__builtin_fma(-d, r, 1.0), r, r);
    r = __builtin_fma(__builtin_fma(-d, r, 1.0), r, r);
    return r;
}
// ---- 1-Newton variant for P4 inner loop (seed >=2^-24 -> <=2^-48) ----
__device__ __forceinline__ double rcp64f(double d) {
    double r;
    asm("v_rcp_f64 %0, %1" : "=v"(r) : "v"(d));
    r = __builtin_fma(__builtin_fma(-d, r, 1.0), r, r);
    return r;
}

// ---- 2^t for t<=0, rel err ~6e-15 (deg-11), branchless ----
__device__ __forceinline__ double exp2n(double t) {
    t = fmax(t, -1000.0);                        // keep exponent splice in range
    double n = __builtin_rint(t);
    double z = (t - n) * 0.69314718055994530942; // |z| <= 0.3466
    double p = 2.5052108385441718775e-8;         // 1/11!
    p = __builtin_fma(p, z, 2.7557319223985892511e-7);
    p = __builtin_fma(p, z, 2.7557319223985890653e-6);
    p = __builtin_fma(p, z, 2.4801587301587301566e-5);
    p = __builtin_fma(p, z, 1.9841269841269841253e-4);
    p = __builtin_fma(p, z, 1.3888888888888889419e-3);
    p = __builtin_fma(p, z, 8.3333333333333332177e-3);
    p = __builtin_fma(p, z, 4.1666666666666664354e-2);
    p = __builtin_fma(p, z, 1.6666666666666666574e-1);
    p = __builtin_fma(p, z, 0.5);
    p = __builtin_fma(p, z, 1.0);
    p = __builtin_fma(p, z, 1.0);
    long long ni = (long long)(int)n;
    return __longlong_as_double(__double_as_longlong(p) + (ni << 52));
}
__device__ __forceinline__ double tanh64(double x) {
    double a = fabs(x);
    double e = exp2n(a * -2.8853900817779268147);  // exp(-2a)
    double r = rcp64(1.0 + e);
    return copysign((1.0 - e) * r, x);
}
__device__ __forceinline__ double sigmoid64(double g) {
    double a = fabs(g);
    double e = exp2n(a * -1.4426950408889634074);  // exp(-a)
    double r = rcp64(1.0 + e);
    double num = (g >= 0.0) ? 1.0 : e;
    return num * r;
}

// ---- tagged-slot publish: one 16B store {v, v^tag}; fire-and-forget ----
__device__ __forceinline__ void pub16(double2* p, double v, unsigned long long tg) {
    v2d t2;
    t2.x = v;
    t2.y = __longlong_as_double(d2ll(v) ^ (long long)tg);
    asm volatile("global_store_dwordx4 %0, %1, off sc0 sc1" :: "v"(p), "v"(t2) : "memory");
}
// ---- tagged-slot gather of 2 adjacent slots (poll until both tags match) ----
__device__ __forceinline__ void gath2(const double2* p, unsigned long long tg,
                                      double* o0, double* o1) {
    v2d a, b;
    for (;;) {
        asm volatile("global_load_dwordx4 %0, %2, off sc0 sc1\n\t"
                     "global_load_dwordx4 %1, %2, off offset:16 sc0 sc1\n\t"
                     "s_waitcnt vmcnt(0)"
                     : "=&v"(a), "=&v"(b) : "v"(p) : "memory");
        bool ok = ((d2ll(a.x) ^ d2ll(a.y)) == (long long)tg) &
                  ((d2ll(b.x) ^ d2ll(b.y)) == (long long)tg);
        if (ok) break;
        __builtin_amdgcn_s_sleep(2);
    }
    *o0 = a.x; *o1 = b.x;
}

// ---------------- init kernel 1: transposes + bias + slot-tag clear ----------------
__global__ __launch_bounds__(256) void k_init_transpose(
    const float* __restrict__ Wih, const float* __restrict__ bih,
    const float* __restrict__ bhh, const float* __restrict__ x,
    float* __restrict__ ws)
{
    char* wsb = (char*)ws;
    float*  wiht = (float*)(wsb + B_WIHT);
    float*  xt   = (float*)(wsb + B_XT);
    double* bias = (double*)(wsb + B_BIAS);
    double2* ex  = (double2*)(wsb + B_EX);
    int i = blockIdx.x * 256 + threadIdx.x;
    if (i < 262144) {                        // W_ih^T [e][r]
        int e = i >> 10, r = i & 1023;
        wiht[i] = Wih[(size_t)r * 256 + e];
    } else if (i < 393216) {                 // x^T [e][s]
        int j = i - 262144; int e = j >> 9, s = j & 511;
        xt[j] = x[(size_t)s * 256 + e];
    } else if (i < 394240) {                 // bias (f64)
        int j = i - 393216;
        bias[j] = (double)bih[j] + (double)bhh[j];
    } else if (i < 394240 + EX_SLOTS) {      // clear exchange slots: x^y=0 != TAG(t)
        double2 z; z.x = 0.0; z.y = 0.0;
        ex[i - 394240] = z;
    }
}

// ---------------- init kernel 2: projections (full f64); ept stores Ta=tanh(ept) ----------------
__global__ __launch_bounds__(512) void k_init_proj(
    const float* __restrict__ x, const float* __restrict__ Wae,
    const float* __restrict__ ba, const float* __restrict__ idec,
    float* __restrict__ ws)
{
    char* wsb = (char*)ws;
    const float* wiht = (const float*)(wsb + B_WIHT);
    const float* xt   = (const float*)(wsb + B_XT);
    double* ept   = (double*)(wsb + B_EPT);
    double* xproj = (double*)(wsb + B_XPROJ);
    double* iproj = (double*)(wsb + B_IPROJ);
    int blk = blockIdx.x, tid = threadIdx.x;
    if (blk < 256) {
        int k = blk, s = tid;
        double a = 0.0;
        for (int e = 0; e < 256; ++e)
            a += (double)Wae[(size_t)k * 256 + e] * (double)xt[(size_t)e * 512 + s];
        ept[(size_t)k * 512 + s] = tanh((double)ba[k] + a);   // Ta (libm, init-time)
    } else if (blk < 256 + 1024) {
        int idx = blk - 256;
        int s = idx >> 1;
        int r = (idx & 1) * 512 + tid;
        double a = 0.0;
        for (int e = 0; e < 256; ++e)
            a += (double)x[(size_t)s * 256 + e] * (double)wiht[(size_t)e * 1024 + r];
        xproj[(size_t)s * 1024 + r] = a;
    } else {
        int r = (blk - 1280) * 512 + tid;
        double a = 0.0;
        for (int e = 0; e < 256; ++e)
            a += (double)idec[e] * (double)wiht[(size_t)e * 1024 + r];
        iproj[r] = a;
    }
}

// ---------------- persistent decode: 256 WGs = 16 groups x 16 slices ----------------
// Per-wave gathers: wave w consumes only k in [32w,32w+32) = slices {2w,2w+1}.
// h/Tb gathers are barrier-free, fan-in-2 polls on parity-double-buffered tagged
// slots.  Only P5's logit poll has fan-in 16 (once per step).
__global__ __launch_bounds__(512, 2) void k_decode(
    const float* __restrict__ gmb, const float* __restrict__ vvec,
    const float* __restrict__ Whh, const float* __restrict__ Wad,
    float* __restrict__ ws, float* __restrict__ out)
{
    extern __shared__ char smem[];
    double* pb   = (double*)(smem + L_PB);
    double* pp3  = (double*)(smem + L_PP3);
    double* pf   = (double*)(smem + L_PF);
    double* vLd  = (double*)(smem + L_VLD);
    double* hf   = (double*)(smem + L_HF);
    double* hwf  = (double*)(smem + L_HWF);      // Tb full
    double* xpro = (double*)(smem + L_XPRO);
    double* mask = (double*)(smem + L_MASK);
    double* c_l  = (double*)(smem + L_CL);
    double* bias_l = (double*)(smem + L_BIAS);
    int*    selA = (int*)(smem + L_SEL);

    const int tid = threadIdx.x;
    const int g = blockIdx.x & 15;      // sample group
    const int q = blockIdx.x >> 4;      // slice

    char* wsb = (char*)ws;
    const double* eptG   = (const double*)(wsb + B_EPT);
    const double* xprojG = (const double*)(wsb + B_XPROJ);
    const double* biasG  = (const double*)(wsb + B_BIAS);
    const double* iprojG = (const double*)(wsb + B_IPROJ);
    double2* exB = (double2*)(wsb + B_EX);

    // ---- one-time LDS fills ----
    for (int i = tid; i < 256; i += 512) vLd[i] = (double)vvec[i];
    if (tid < 64) bias_l[tid] = biasG[((tid >> 4) << 8) + q * 16 + (tid & 15)];
    for (int i = tid; i < 256; i += 512) mask[i] = 0.0;
    for (int i = tid; i < 128; i += 512) c_l[i] = 0.0;
    for (int i = tid; i < 2080; i += 512) { hf[i] = 0.0; hwf[i] = 0.0; }
    {
        int sl = tid >> 6, rl = tid & 63;
        int rg = ((rl >> 4) << 8) + q * 16 + (rl & 15);
        xpro[sl * 64 + rl] = iprojG[rg];
    }

    const int w = tid >> 6, lane = tid & 63;
    const int kc4 = tid >> 5, ss = tid & 31;     // P4 thread geometry

    // ---- step-invariant register loads ----
    // Ta for this thread's (kc4, ss): 16 f64 regs (was re-read from LDS every phase)
    double ev[16];
    #pragma unroll
    for (int kk = 0; kk < 16; ++kk)
        ev[kk] = eptG[(size_t)(kc4 * 16 + kk) * 512 + q * 32 + ss];
    // W_hh slice
    const int rg1 = ((lane >> 4) << 8) + q * 16 + (lane & 15);
    const int kbase = w * 32;
    float wreg[32];
    {
        const float4* wrow = (const float4*)(Whh + (size_t)rg1 * 256 + kbase);
        #pragma unroll
        for (int j = 0; j < 8; ++j) {
            float4 v4 = wrow[j];
            wreg[4 * j + 0] = v4.x; wreg[4 * j + 1] = v4.y;
            wreg[4 * j + 2] = v4.z; wreg[4 * j + 3] = v4.w;
        }
    }
    float w3[8];
    {
        const float* wr3 = Wad + (size_t)(q * 16 + (tid & 15)) * 256 + (tid >> 4) * 8;
        #pragma unroll
        for (int kk = 0; kk < 8; ++kk) w3[kk] = wr3[kk];
    }
    __syncthreads();

    double lps = 0.0;

    for (int t = 0; t < SN; ++t) {
        const unsigned long long tg = (unsigned long long)(t + 2) * TAGC;
        double2* parB   = exB + (size_t)(t & 1) * PAR_STRIDE;
        double2* hexP   = parB + (size_t)g * 2048;
        double2* waexP  = parB + 32768 + (size_t)g * 2048;
        double2* lexP   = parB + 65536 + (size_t)g * 4096;

        // ---- gumbel prefetch (wave w <-> sample w) ----
        float gv8[8];
        {
            const float* growW = gmb + (size_t)t * (BN * SN) + (size_t)(g * 8 + w) * SN;
            #pragma unroll
            for (int j = 0; j < 8; ++j)
                gv8[j] = __builtin_nontemporal_load(growW + lane + 64 * j);
        }

        // ================= P1(A): gate partials (f64), sl 0-3 =================
        #pragma unroll
        for (int slin = 0; slin < 4; ++slin) {
            int sl = slin;
            double a0 = 0.0, a1 = 0.0, a2 = 0.0, a3 = 0.0;
            #pragma unroll
            for (int g4 = 0; g4 < 8; ++g4) {
                const double* hp = hf + sl * 260 + kbase + 4 * g4;
                double2 hA = *(const double2*)(hp);
                double2 hB = *(const double2*)(hp + 2);
                a0 += (double)wreg[4 * g4 + 0] * hA.x;
                a1 += (double)wreg[4 * g4 + 1] * hA.y;
                a2 += (double)wreg[4 * g4 + 2] * hB.x;
                a3 += (double)wreg[4 * g4 + 3] * hB.y;
            }
            pb[w * 576 + lane * 9 + sl] = ((a0 + a1) + (a2 + a3));
        }
        __syncthreads();   // S1: pb(A) complete before w0 reads

        // ---- P2(A): f64 LSTM cell by wave 0; publish h(A) tagged ----
        if (w == 0) {
            int jl = lane & 15, slin = lane >> 4;
            int sl = slin;
            double gvv[4];
            #pragma unroll
            for (int gate = 0; gate < 4; ++gate) {
                int rl = gate * 16 + jl;
                double p0 = pb[0 * 576 + rl * 9 + sl], p1 = pb[1 * 576 + rl * 9 + sl];
                double p2 = pb[2 * 576 + rl * 9 + sl], p3 = pb[3 * 576 + rl * 9 + sl];
                double p4 = pb[4 * 576 + rl * 9 + sl], p5 = pb[5 * 576 + rl * 9 + sl];
                double p6 = pb[6 * 576 + rl * 9 + sl], p7 = pb[7 * 576 + rl * 9 + sl];
                double s8 = ((p0 + p1) + (p2 + p3)) + ((p4 + p5) + (p6 + p7));
                gvv[gate] = bias_l[rl] + xpro[sl * 64 + rl] + s8;
            }
            double si = sigmoid64(gvv[0]);
            double sf = sigmoid64(gvv[1]);
            double so = sigmoid64(gvv[3]);
            double cf = sf * c_l[jl * 8 + sl] + si * tanh64(gvv[2]);
            double hn = so * tanh64(cf);
            c_l[jl * 8 + sl] = cf;
            pub16(&hexP[sl * 256 + q * 16 + jl], hn, tg);
        }

        // ================= P1(B): gate partials, sl 4-7 =================
        #pragma unroll
        for (int slin = 0; slin < 4; ++slin) {
            int sl = 4 + slin;
            double a0 = 0.0, a1 = 0.0, a2 = 0.0, a3 = 0.0;
            #pragma unroll
            for (int g4 = 0; g4 < 8; ++g4) {
                const double* hp = hf + sl * 260 + kbase + 4 * g4;
                double2 hA = *(const double2*)(hp);
                double2 hB = *(const double2*)(hp + 2);
                a0 += (double)wreg[4 * g4 + 0] * hA.x;
                a1 += (double)wreg[4 * g4 + 1] * hA.y;
                a2 += (double)wreg[4 * g4 + 2] * hB.x;
                a3 += (double)wreg[4 * g4 + 3] * hB.y;
            }
            pb[w * 576 + lane * 9 + sl] = ((a0 + a1) + (a2 + a3));
        }
        __syncthreads();   // S2: pb(B) complete before w1 reads

        // ---- P2(B): f64 LSTM cell by wave 1; publish h(B) tagged ----
        if (w == 1) {
            int jl = lane & 15, slin = lane >> 4;
            int sl = 4 + slin;
            double gvv[4];
            #pragma unroll
            for (int gate = 0; gate < 4; ++gate) {
                int rl = gate * 16 + jl;
                double p0 = pb[0 * 576 + rl * 9 + sl], p1 = pb[1 * 576 + rl * 9 + sl];
                double p2 = pb[2 * 576 + rl * 9 + sl], p3 = pb[3 * 576 + rl * 9 + sl];
                double p4 = pb[4 * 576 + rl * 9 + sl], p5 = pb[5 * 576 + rl * 9 + sl];
                double p6 = pb[6 * 576 + rl * 9 + sl], p7 = pb[7 * 576 + rl * 9 + sl];
                double s8 = ((p0 + p1) + (p2 + p3)) + ((p4 + p5) + (p6 + p7));
                gvv[gate] = bias_l[rl] + xpro[sl * 64 + rl] + s8;
            }
            double si = sigmoid64(gvv[0]);
            double sf = sigmoid64(gvv[1]);
            double so = sigmoid64(gvv[3]);
            double cf = sf * c_l[jl * 8 + sl] + si * tanh64(gvv[2]);
            double hn = so * tanh64(cf);
            c_l[jl * 8 + sl] = cf;
            pub16(&hexP[sl * 256 + q * 16 + jl], hn, tg);
        }

        // ---- gather h(A): PER-WAVE, fan-in 2, no barrier ----
        {
            int sl = lane >> 4;                 // 0..3
            int k  = kbase + (lane & 15) * 2;   // wave's own k-range
            gath2(hexP + sl * 256 + k, tg, &hf[sl * 260 + k], &hf[sl * 260 + k + 1]);
        }

        // ================= P3(A): hWa partials (f64), sl 0-3 =================
        {
            int kc = tid >> 4, rl = tid & 15;
            #pragma unroll
            for (int sl = 0; sl < 4; ++sl) {
                double a = 0.0;
                #pragma unroll
                for (int kk = 0; kk < 8; ++kk)
                    a += (double)w3[kk] * hf[sl * 260 + kc * 8 + kk];
                pp3[kc * 144 + rl * 9 + sl] = a;
            }
        }
        __syncthreads();   // S3: pp3(A) complete before w2 reads
        // ---- P3(A) reduce by wave 2; publish Tb(A)=tanh(hWa) tagged ----
        if (w == 2) {
            int rl = lane & 15, slin = lane >> 4;
            int sl = slin;
            double s = 0.0;
            for (int kc = 0; kc < 32; ++kc) s += pp3[kc * 144 + rl * 9 + sl];
            pub16(&waexP[sl * 256 + q * 16 + rl], tanh64(s), tg);
        }

        // ---- gather h(B): PER-WAVE ----
        {
            int sl = 4 + (lane >> 4);
            int k  = kbase + (lane & 15) * 2;
            gath2(hexP + sl * 256 + k, tg, &hf[sl * 260 + k], &hf[sl * 260 + k + 1]);
        }

        // ================= P3(B): hWa partials, sl 4-7 (disjoint pp3 columns) ====
        {
            int kc = tid >> 4, rl = tid & 15;
            #pragma unroll
            for (int slin = 0; slin < 4; ++slin) {
                int sl = 4 + slin;
                double a = 0.0;
                #pragma unroll
                for (int kk = 0; kk < 8; ++kk)
                    a += (double)w3[kk] * hf[sl * 260 + kc * 8 + kk];
                pp3[kc * 144 + rl * 9 + sl] = a;
            }
        }
        __syncthreads();   // S4: pp3(B) complete before w3 reads
        // ---- P3(B) reduce by wave 3; publish Tb(B) tagged ----
        if (w == 3) {
            int rl = lane & 15, slin = lane >> 4;
            int sl = 4 + slin;
            double s = 0.0;
            for (int kc = 0; kc < 32; ++kc) s += pp3[kc * 144 + rl * 9 + sl];
            pub16(&waexP[sl * 256 + q * 16 + rl], tanh64(s), tg);
        }

        // ---- gather Tb(A): PER-WAVE ----
        {
            int sl = lane >> 4;
            int k  = kbase + (lane & 15) * 2;
            gath2(waexP + sl * 256 + k, tg, &hwf[sl * 260 + k], &hwf[sl * 260 + k + 1]);
        }

        // ================= P4(A): attention partials (tanh-addition), sl 0-3 ============
        {
            double vd[16];
            #pragma unroll
            for (int kk = 0; kk < 16; ++kk) vd[kk] = vLd[kc4 * 16 + kk];
            #pragma unroll 1
            for (int sl = 0; sl < 4; ++sl) {
                double a = 0.0;
                #pragma unroll
                for (int j = 0; j < 8; ++j) {
                    double2 h2 = *(const double2*)(hwf + sl * 260 + kc4 * 16 + 2 * j); // Tb
                    {
                        double Ta = ev[2 * j + 0], Tb = h2.x;
                        double d = __builtin_fma(Ta, Tb, 1.0);
                        double r = rcp64f(d);
                        a = __builtin_fma(vd[2 * j + 0], (Ta + Tb) * r, a);
                    }
                    {
                        double Ta = ev[2 * j + 1], Tb = h2.y;
                        double d = __builtin_fma(Ta, Tb, 1.0);
                        double r = rcp64f(d);
                        a = __builtin_fma(vd[2 * j + 1], (Ta + Tb) * r, a);
                    }
                }
                pf[kc4 * 288 + ss * 9 + sl] = a;
            }
        }
        __syncthreads();   // S5: pf(A) complete before reduce
        // ---- P4(A) reduce by waves 0-1; publish logits(A) tagged ----
        if (tid < 128) {
            int sA = tid & 31, slin = tid >> 5;
            int sl = slin;
            double u = 0.0;
            for (int kc = 0; kc < 16; ++kc) u += pf[kc * 288 + sA * 9 + sl];
            double lg = 10.0 * tanh64(u);
            pub16(&lexP[sl * 512 + q * 32 + sA], lg + mask[sA * 8 + sl], tg);
        }

        // ---- gather Tb(B): PER-WAVE ----
        {
            int sl = 4 + (lane >> 4);
            int k  = kbase + (lane & 15) * 2;
            gath2(waexP + sl * 256 + k, tg, &hwf[sl * 260 + k], &hwf[sl * 260 + k + 1]);
        }

        // ================= P4(B): attention partials, sl 4-7 ============
        {
            double vd[16];
            #pragma unroll
            for (int kk = 0; kk < 16; ++kk) vd[kk] = vLd[kc4 * 16 + kk];
            #pragma unroll 1
            for (int slin = 0; slin < 4; ++slin) {
                int sl = 4 + slin;
                double a = 0.0;
                #pragma unroll
                for (int j = 0; j < 8; ++j) {
                    double2 h2 = *(const double2*)(hwf + sl * 260 + kc4 * 16 + 2 * j);
                    {
                        double Ta = ev[2 * j + 0], Tb = h2.x;
                        double d = __builtin_fma(Ta, Tb, 1.0);
                        double r = rcp64f(d);
                        a = __builtin_fma(vd[2 * j + 0], (Ta + Tb) * r, a);
                    }
                    {
                        double Ta = ev[2 * j + 1], Tb = h2.y;
                        double d = __builtin_fma(Ta, Tb, 1.0);
                        double r = rcp64f(d);
                        a = __builtin_fma(vd[2 * j + 1], (Ta + Tb) * r, a);
                    }
                }
                pf[kc4 * 288 + ss * 9 + sl] = a;
            }
        }
        __syncthreads();   // S6: pf(B) complete before reduce
        // ---- P4(B) reduce by waves 0-1; publish logits(B) tagged ----
        if (tid < 128) {
            int sA = tid & 31, slin = tid >> 5;
            int sl = 4 + slin;
            double u = 0.0;
            for (int kc = 0; kc < 16; ++kc) u += pf[kc * 288 + sA * 9 + sl];
            double lg = 10.0 * tanh64(u);
            pub16(&lexP[sl * 512 + q * 32 + sA], lg + mask[sA * 8 + sl], tg);
        }

        // ================= P5: poll 8 tagged logit slots (fan-in 16); f64 argmax ======
        {
            const double2* b0 = lexP + (size_t)w * 512 + lane;
            const double2* b1 = b0 + 256;
            double lv[8];
            for (;;) {
                v2d q0, q1, q2, q3, q4, q5, q6, q7;
                asm volatile(
                    "global_load_dwordx4 %0, %8, off sc0 sc1\n\t"
                    "global_load_dwordx4 %1, %8, off offset:1024 sc0 sc1\n\t"
                    "global_load_dwordx4 %2, %8, off offset:2048 sc0 sc1\n\t"
                    "global_load_dwordx4 %3, %8, off offset:3072 sc0 sc1\n\t"
                    "global_load_dwordx4 %4, %9, off sc0 sc1\n\t"
                    "global_load_dwordx4 %5, %9, off offset:1024 sc0 sc1\n\t"
                    "global_load_dwordx4 %6, %9, off offset:2048 sc0 sc1\n\t"
                    "global_load_dwordx4 %7, %9, off offset:3072 sc0 sc1\n\t"
                    "s_waitcnt vmcnt(0)"
                    : "=&v"(q0), "=&v"(q1), "=&v"(q2), "=&v"(q3),
                      "=&v"(q4), "=&v"(q5), "=&v"(q6), "=&v"(q7)
                    : "v"(b0), "v"(b1) : "memory");
                bool ok = ((d2ll(q0.x) ^ d2ll(q0.y)) == (long long)tg) &
                          ((d2ll(q1.x) ^ d2ll(q1.y)) == (long long)tg) &
                          ((d2ll(q2.x) ^ d2ll(q2.y)) == (long long)tg) &
                          ((d2ll(q3.x) ^ d2ll(q3.y)) == (long long)tg) &
                          ((d2ll(q4.x) ^ d2ll(q4.y)) == (long long)tg) &
                          ((d2ll(q5.x) ^ d2ll(q5.y)) == (long long)tg) &
                          ((d2ll(q6.x) ^ d2ll(q6.y)) == (long long)tg) &
                          ((d2ll(q7.x) ^ d2ll(q7.y)) == (long long)tg);
                if (ok) {
                    lv[0] = q0.x; lv[1] = q1.x; lv[2] = q2.x; lv[3] = q3.x;
                    lv[4] = q4.x; lv[5] = q5.x; lv[6] = q6.x; lv[7] = q7.x;
                    break;
                }
                __builtin_amdgcn_s_sleep(2);
            }
            double M = -INFINITY;
            #pragma unroll
            for (int j = 0; j < 8; ++j) M = fmax(M, lv[j]);
            #pragma unroll
            for (int off = 32; off >= 1; off >>= 1) M = fmax(M, __shfl_xor(M, off, 64));
            float se = 0.f;
            #pragma unroll
            for (int j = 0; j < 8; ++j) se += expf((float)(lv[j] - M));
            #pragma unroll
            for (int off = 32; off >= 1; off >>= 1) se += __shfl_xor(se, off, 64);
            float logS = logf(se);
            double best = -INFINITY; int bidx = 0x7fffffff; double bl = 0.0;
            #pragma unroll
            for (int j = 0; j < 8; ++j) {
                int s = lane + 64 * j;
                double cd = lv[j] + (double)gv8[j];   // softmax shift cancels in argmax
                if (cd > best || (cd == best && s < bidx)) { best = cd; bidx = s; bl = lv[j]; }
            }
            #pragma unroll
            for (int off = 32; off >= 1; off >>= 1) {
                double ob = __shfl_xor(best, off, 64);
                int    oi = __shfl_xor(bidx, off, 64);
                double ol = __shfl_xor(bl, off, 64);
                if (ob > best || (ob == best && oi < bidx)) { best = ob; bidx = oi; bl = ol; }
            }
            lps += (bl - M) - (double)logS;
            if (lane == 0) {
                selA[w] = bidx;
                if (q == 0) out[(size_t)(g * 8 + w) * SN + t] = (float)bidx;
            }
        }
        __syncthreads();   // S7: selA visible to all
        // ---- mask update + next-step xpro gather ----
        if (tid < 256) {
            int sA = tid >> 3, sl = tid & 7;
            if (selA[sl] == q * 32 + sA) mask[sA * 8 + sl] = -INFINITY;
        }
        {
            int sl = tid >> 6, rl = tid & 63;
            int rg = ((rl >> 4) << 8) + q * 16 + (rl & 15);
            xpro[sl * 64 + rl] = xprojG[(size_t)selA[sl] * 1024 + rg];
        }
        // no end-of-step barrier: next P1 reads hf (wave-private) and writes pb
        // (wave-own region); xpro/mask/selA consumers are separated by S1..S5.
    }
    if (q == 0 && lane == 0) out[(size_t)BN * SN + g * 8 + w] = (float)lps;
}

extern "C" void kernel_launch(void* const* d_in, const int* in_sizes, int n_in,
                              void* d_out, int out_size, void* d_ws, size_t ws_size,
                              hipStream_t stream)
{
    const float* x    = (const float*)d_in[0];
    const float* gmb  = (const float*)d_in[1];
    const float* Wih  = (const float*)d_in[2];
    const float* Whh  = (const float*)d_in[3];
    const float* bih  = (const float*)d_in[4];
    const float* bhh  = (const float*)d_in[5];
    const float* Wad  = (const float*)d_in[6];
    const float* Wae  = (const float*)d_in[7];
    const float* ba   = (const float*)d_in[8];
    const float* vvec = (const float*)d_in[9];
    const float* idec = (const float*)d_in[10];
    float* ws = (float*)d_ws;
    float* out = (float*)d_out;

    hipFuncSetAttribute(reinterpret_cast<const void*>(k_decode),
                        hipFuncAttributeMaxDynamicSharedMemorySize, SMEM_TOTAL);

    hipLaunchKernelGGL(k_init_transpose, dim3(2564), dim3(256), 0, stream,
                       Wih, bih, bhh, x, ws);
    hipLaunchKernelGGL(k_init_proj, dim3(1282), dim3(512), 0, stream,
                       x, Wae, ba, idec, ws);
    hipLaunchKernelGGL(k_decode, dim3(256), dim3(512), SMEM_TOTAL, stream,
                       gmb, vvec, Whh, Wad, ws, out);
}